// Round 1
// 1545.989 us; speedup vs baseline: 1.7296x; 1.7296x over previous
//
#include <hip/hip_runtime.h>
#include <math.h>

#define NTOK 16384
#define DIM 512
#define QLV 8
#define KCODE 1024
#define BM 64
#define DC 8
#define NCH (DIM / DC)  // 64 d-chunks (old path)
#define TAU 1e-3f       // raised from 5e-4: bf16x3 MFMA adds <=2.5e-4 abs error; TAU >= 2*eps

// ---- MFMA path constants ----
#define NCK 16          // 16 chunks of 32 d
#define CHUNKB 131072   // bytes per chunk in split-cb: 2 halves x (hi+lo) x 512 codes x 64 B
#define CBSPLIT_FLOAT_OFF 65536  // float offset of split-cb region inside ws (256 KB in)

typedef __attribute__((ext_vector_type(4))) float f32x4;
typedef __attribute__((ext_vector_type(8))) short bf16x8;

__global__ __launch_bounds__(256) void zero_ws(float* ws) {
  int i = blockIdx.x * 256 + threadIdx.x;
  for (int k = i; k < QLV * KCODE + 2 * QLV; k += gridDim.x * 256) ws[k] = 0.f;
}

// ---- numpy float32 replication helpers (PROVEN in round 4 — do not touch) --
__device__ __forceinline__ float np_blk128_sq(const float* __restrict__ x) {
#pragma clang fp contract(off)
  float L[16];
#pragma unroll
  for (int j = 0; j < 16; ++j) {
    const float a0 = x[j] * x[j];
    const float a1 = x[16 + j] * x[16 + j];
    const float a2 = x[32 + j] * x[32 + j];
    const float a3 = x[48 + j] * x[48 + j];
    const float a4 = x[64 + j] * x[64 + j];
    const float a5 = x[80 + j] * x[80 + j];
    const float a6 = x[96 + j] * x[96 + j];
    const float a7 = x[112 + j] * x[112 + j];
    L[j] = ((a0 + a1) + (a2 + a3)) + ((a4 + a5) + (a6 + a7));
  }
  float T3[8];
#pragma unroll
  for (int i = 0; i < 8; ++i) T3[i] = L[i] + L[i + 8];
  float T6[4];
#pragma unroll
  for (int j = 0; j < 4; ++j) T6[j] = T3[j] + T3[j + 4];
  return (T6[0] + T6[2]) + (T6[1] + T6[3]);
}

__device__ __forceinline__ float np_sum512_sq(const float* __restrict__ x) {
#pragma clang fp contract(off)
  const float p0 = np_blk128_sq(x);
  const float p1 = np_blk128_sq(x + 128);
  const float p2 = np_blk128_sq(x + 256);
  const float p3 = np_blk128_sq(x + 384);
  const float s01 = p0 + p1;
  const float s23 = p2 + p3;
  return s01 + s23;
}

__device__ __forceinline__ float np_dist(float A, const float* __restrict__ r,
                                         const float* __restrict__ c, float cn) {
#pragma clang fp contract(off)
  float b1 = 0.f;
#pragma unroll 8
  for (int d = 0; d < 384; ++d) b1 = __builtin_fmaf(r[d], c[d], b1);
  float b2 = 0.f;
#pragma unroll 8
  for (int d = 384; d < 512; ++d) b2 = __builtin_fmaf(r[d], c[d], b2);
  const float B = b1 + b2;
  const float t1 = 2.0f * B;
  const float t2 = A - t1;
  return t2 + cn;
}
// ---------------------------------------------------------------------------

__global__ __launch_bounds__(256) void cnorm_np_kernel(const float* __restrict__ cb,
                                                       float* __restrict__ cn) {
  const int row = blockIdx.x * 256 + threadIdx.x;  // [0, Q*K)
  cn[row] = np_sum512_sq(cb + (size_t)row * DIM);
}

// lexicographic (val, idx) less-than
__device__ __forceinline__ bool lt2(float a, int ia, float b, int ib) {
  return a < b || (a == b && ia < ib);
}

// ---- bf16 split helpers (RTNE) ----
__device__ __forceinline__ unsigned short bf16_rtne(float x) {
  unsigned u = __builtin_bit_cast(unsigned, x);
  u += 0x7FFFu + ((u >> 16) & 1u);
  return (unsigned short)(u >> 16);
}
__device__ __forceinline__ float bf16_tof(unsigned short h) {
  unsigned u = (unsigned)h << 16;
  return __builtin_bit_cast(float, u);
}
__device__ __forceinline__ void split2(float x, unsigned short& h, unsigned short& l) {
  h = bf16_rtne(x);
  l = bf16_rtne(x - bf16_tof(h));
}

__device__ __forceinline__ void gload16(const void* g, void* l) {
  __builtin_amdgcn_global_load_lds(
      (const __attribute__((address_space(1))) unsigned int*)g,
      (__attribute__((address_space(3))) unsigned int*)l, 16, 0, 0);
}

// One-time: split fp32 codebooks into pre-swizzled bf16 hi/lo tiles in ws.
// Layout per (q,chunk): [half(2)][hl(2)][512 codes][64 B], swizzled slot =
// kb ^ ((cl>>1)&3) so that linear global_load_lds fills a conflict-free LDS image.
__global__ __launch_bounds__(256) void split_cb_kernel(const float* __restrict__ cb,
                                                       unsigned short* __restrict__ dst) {
  const int f = blockIdx.x * 256 + threadIdx.x;  // float4 index, 2^20 total
  const int d4 = f & 127;
  const int c = (f >> 7) & 1023;
  const int q = f >> 17;
  const float4 v = *(const float4*)(cb + (size_t)f * 4);
  const int d0 = d4 * 4;
  const int dc = d0 >> 5;
  const int e = d0 & 31;
  const int kb = e >> 3;
  const int e7 = e & 7;  // 0 or 4
  const int half = c >> 9, cl = c & 511;
  const int slot = kb ^ ((cl >> 1) & 3);
  const size_t base = (size_t)(q * NCK + dc) * CHUNKB + (size_t)half * 65536;
  const size_t off = base + (size_t)cl * 64 + (size_t)slot * 16 + (size_t)e7 * 2;
  unsigned short h0, l0, h1, l1, h2, l2, h3, l3;
  split2(v.x, h0, l0);
  split2(v.y, h1, l1);
  split2(v.z, h2, l2);
  split2(v.w, h3, l3);
  uint2 hv, lv;
  hv.x = (unsigned)h0 | ((unsigned)h1 << 16);
  hv.y = (unsigned)h2 | ((unsigned)h3 << 16);
  lv.x = (unsigned)l0 | ((unsigned)l1 << 16);
  lv.y = (unsigned)l2 | ((unsigned)l3 << 16);
  char* db = (char*)dst;
  *(uint2*)(db + off) = hv;            // hi plane
  *(uint2*)(db + off + 32768) = lv;    // lo plane
}

// ===================== MFMA level kernel =====================
// Block: 64 tokens x 1024 codes, 512 threads (8 waves).
// Wave w: code-frags cf = h*32 + w + 8*j (j=0..3) per half h; token-frags tf=0..3.
// acc[h][j][tf] via 3x mfma_f32_16x16x32_bf16 (hi*hi + lo*hi + hi*lo).
template <bool FIRST, bool LAST>
__global__ __launch_bounds__(512, 2) void level_mfma(
    const float* __restrict__ x, float* __restrict__ resid,
    const float* __restrict__ cb, const unsigned short* __restrict__ cbsplit,
    const float* __restrict__ cnorm, float* __restrict__ out_idx,
    float* __restrict__ counts, float* __restrict__ commit, int* __restrict__ rcnt,
    int* __restrict__ rlist, int qlev) {
  __shared__ __align__(16) unsigned char Bs[131072];       // [half][hl][512][64B]
  __shared__ __align__(16) unsigned char As[16384];        // [buf][hl][64][64B]
  __shared__ __align__(16) float foldb[64][8][4];
  __shared__ int chosen[64];

  const int tid = threadIdx.x;
  const int lane = tid & 63;
  const int w = tid >> 6;
  const int col = lane & 15;
  const int kb = lane >> 4;
  const int blk = blockIdx.x;
  const float* rin = FIRST ? x : resid;
  const char* csp = (const char*)cbsplit;

  // A-staging geometry: thread -> (row, 4 d's)
  const int arow = tid >> 3;
  const int ae0 = (tid & 7) * 4;
  const int akb = ae0 >> 3;
  const int aslot = akb ^ ((arow >> 1) & 3);
  const size_t abyte = (size_t)arow * 64 + (size_t)aslot * 16 + (size_t)(ae0 & 7) * 2;
  const float* aglob = rin + (size_t)(blk * BM + arow) * DIM + ae0;

  f32x4 acc[2][4][4];
#pragma unroll
  for (int h = 0; h < 2; ++h)
#pragma unroll
    for (int j = 0; j < 4; ++j)
#pragma unroll
      for (int tf = 0; tf < 4; ++tf) acc[h][j][tf] = (f32x4){0.f, 0.f, 0.f, 0.f};

  // ---- prologue: A(0) split->LDS buf0, then issue H0(chunk 0) loads ----
  {
    const float4 pA = *(const float4*)aglob;
    unsigned short h0, l0, h1, l1, h2, l2, h3, l3;
    split2(pA.x, h0, l0);
    split2(pA.y, h1, l1);
    split2(pA.z, h2, l2);
    split2(pA.w, h3, l3);
    uint2 hv, lv;
    hv.x = (unsigned)h0 | ((unsigned)h1 << 16);
    hv.y = (unsigned)h2 | ((unsigned)h3 << 16);
    lv.x = (unsigned)l0 | ((unsigned)l1 << 16);
    lv.y = (unsigned)l2 | ((unsigned)l3 << 16);
    *(uint2*)&As[abyte] = hv;
    *(uint2*)&As[4096 + abyte] = lv;
  }
  {
    const char* s = csp + (size_t)w * 8192 + (size_t)lane * 16;
    unsigned char* d = &Bs[(size_t)w * 8192];
#pragma unroll
    for (int i = 0; i < 8; ++i) gload16(s + i * 1024, d + i * 1024);
  }

  float4 pAn;
  for (int dc = 0; dc < NCK; ++dc) {
    const char* src = csp + (size_t)dc * CHUNKB;
    const int abuf = dc & 1;
    // ================= phase 0: compute half0, stage H1(dc) =================
    __syncthreads();  // H0(dc) loads drained; A(dc) writes visible
    {
      const char* s = src + 65536 + (size_t)w * 8192 + (size_t)lane * 16;
      unsigned char* d = &Bs[65536 + (size_t)w * 8192];
#pragma unroll
      for (int i = 0; i < 8; ++i) gload16(s + i * 1024, d + i * 1024);
    }
    if (dc + 1 < NCK) pAn = *(const float4*)(aglob + (dc + 1) * 32);

    bf16x8 ah[4], al[4];
#pragma unroll
    for (int tf = 0; tf < 4; ++tf) {
      const int row = tf * 16 + col;
      const size_t slot16 = (size_t)((kb ^ ((row >> 1) & 3)) * 16);
      const size_t ab = (size_t)abuf * 8192 + (size_t)row * 64 + slot16;
      ah[tf] = *(const bf16x8*)&As[ab];
      al[tf] = *(const bf16x8*)&As[ab + 4096];
    }
#pragma unroll
    for (int j = 0; j < 4; ++j) {
      const int cl = (w + 8 * j) * 16 + col;
      const size_t bb = (size_t)cl * 64 + (size_t)((kb ^ ((cl >> 1) & 3)) * 16);
      const bf16x8 bh = *(const bf16x8*)&Bs[bb];
      const bf16x8 bl = *(const bf16x8*)&Bs[32768 + bb];
#pragma unroll
      for (int tf = 0; tf < 4; ++tf) {
        acc[0][j][tf] = __builtin_amdgcn_mfma_f32_16x16x32_bf16(ah[tf], bh, acc[0][j][tf], 0, 0, 0);
        acc[0][j][tf] = __builtin_amdgcn_mfma_f32_16x16x32_bf16(al[tf], bh, acc[0][j][tf], 0, 0, 0);
        acc[0][j][tf] = __builtin_amdgcn_mfma_f32_16x16x32_bf16(ah[tf], bl, acc[0][j][tf], 0, 0, 0);
      }
    }
    // ================= phase 1: compute half1, stage H0(dc+1) ===============
    __syncthreads();  // H1(dc) loads drained; pAn in regs
    if (dc + 1 < NCK) {
      const char* s2 = csp + (size_t)(dc + 1) * CHUNKB + (size_t)w * 8192 + (size_t)lane * 16;
      unsigned char* d2 = &Bs[(size_t)w * 8192];
#pragma unroll
      for (int i = 0; i < 8; ++i) gload16(s2 + i * 1024, d2 + i * 1024);
      unsigned short h0, l0, h1, l1, h2, l2, h3, l3;
      split2(pAn.x, h0, l0);
      split2(pAn.y, h1, l1);
      split2(pAn.z, h2, l2);
      split2(pAn.w, h3, l3);
      uint2 hv, lv;
      hv.x = (unsigned)h0 | ((unsigned)h1 << 16);
      hv.y = (unsigned)h2 | ((unsigned)h3 << 16);
      lv.x = (unsigned)l0 | ((unsigned)l1 << 16);
      lv.y = (unsigned)l2 | ((unsigned)l3 << 16);
      const size_t ab0 = (size_t)(abuf ^ 1) * 8192 + abyte;
      *(uint2*)&As[ab0] = hv;
      *(uint2*)&As[ab0 + 4096] = lv;
    }
#pragma unroll
    for (int j = 0; j < 4; ++j) {
      const int cl = (w + 8 * j) * 16 + col;
      const size_t bb = (size_t)cl * 64 + (size_t)((kb ^ ((cl >> 1) & 3)) * 16);
      const bf16x8 bh = *(const bf16x8*)&Bs[65536 + bb];
      const bf16x8 bl = *(const bf16x8*)&Bs[65536 + 32768 + bb];
#pragma unroll
      for (int tf = 0; tf < 4; ++tf) {
        acc[1][j][tf] = __builtin_amdgcn_mfma_f32_16x16x32_bf16(ah[tf], bh, acc[1][j][tf], 0, 0, 0);
        acc[1][j][tf] = __builtin_amdgcn_mfma_f32_16x16x32_bf16(al[tf], bh, acc[1][j][tf], 0, 0, 0);
        acc[1][j][tf] = __builtin_amdgcn_mfma_f32_16x16x32_bf16(ah[tf], bl, acc[1][j][tf], 0, 0, 0);
      }
    }
  }

  // ---- epilogue: fold top-2 per token over this wave's 128 codes ----
  float cnv[2][4];
#pragma unroll
  for (int h = 0; h < 2; ++h)
#pragma unroll
    for (int j = 0; j < 4; ++j) cnv[h][j] = cnorm[(h * 32 + w + 8 * j) * 16 + col];

#pragma unroll
  for (int tf = 0; tf < 4; ++tf) {
#pragma unroll
    for (int r = 0; r < 4; ++r) {
      float b1 = 3.4e38f, b2 = 3.4e38f;
      int x1 = KCODE, x2 = KCODE;
#pragma unroll
      for (int h = 0; h < 2; ++h)
#pragma unroll
        for (int j = 0; j < 4; ++j) {
          const int c = (h * 32 + w + 8 * j) * 16 + col;
          const float dist = fmaf(-2.f, acc[h][j][tf][r], cnv[h][j]);
          if (lt2(dist, c, b1, x1)) {
            b2 = b1; x2 = x1; b1 = dist; x1 = c;
          } else if (lt2(dist, c, b2, x2)) {
            b2 = dist; x2 = c;
          }
        }
      // butterfly across the 16 lanes of this col-group
#pragma unroll
      for (int off = 1; off < 16; off <<= 1) {
        const float w1 = __shfl_xor(b1, off);
        const int j1 = __shfl_xor(x1, off);
        const float w2 = __shfl_xor(b2, off);
        const int j2 = __shfl_xor(x2, off);
        if (lt2(w1, j1, b1, x1)) {
          if (lt2(b1, x1, w2, j2)) { b2 = b1; x2 = x1; }
          else { b2 = w2; x2 = j2; }
          b1 = w1; x1 = j1;
        } else if (lt2(w1, j1, b2, x2)) {
          b2 = w1; x2 = j1;
        }
      }
      if (col == 0) {
        const int t = tf * 16 + (lane >> 4) * 4 + r;
        float4 fv;
        fv.x = b1; fv.y = __int_as_float(x1); fv.z = b2; fv.w = __int_as_float(x2);
        *(float4*)&foldb[t][w][0] = fv;
      }
    }
  }
  __syncthreads();

  // ---- merge 8 wave-results per token; gap test; decide/rescue ----
  if (tid < 64) {
    float V1 = 3.4e38f, V2 = 3.4e38f;
    int I1 = KCODE, I2 = KCODE;
#pragma unroll
    for (int ww = 0; ww < 8; ++ww) {
      const float4 e = *(const float4*)&foldb[tid][ww][0];
      const float a1 = e.x, a2 = e.z;
      const int a1i = __float_as_int(e.y), a2i = __float_as_int(e.w);
      if (lt2(a1, a1i, V1, I1)) {
        if (lt2(V1, I1, a2, a2i)) { V2 = V1; I2 = I1; }
        else { V2 = a2; I2 = a2i; }
        V1 = a1; I1 = a1i;
      } else if (lt2(a1, a1i, V2, I2)) {
        V2 = a1; I2 = a1i;
      }
    }
    if (V2 - V1 < TAU) {  // near-tie: np-fp32 rescue decides
      const int pos = atomicAdd(rcnt, 1);
      rlist[pos] = blk * BM + tid;
      chosen[tid] = -1;
    } else {
      chosen[tid] = I1;
      out_idx[(size_t)(blk * BM + tid) * QLV + qlev] = (float)I1;
      atomicAdd(&counts[I1], 1.0f);
    }
  }
  __syncthreads();
  {  // residual update (fp32 chain, bit-equal to np's) — fast-path tokens only
    const int tb = tid >> 3, part = tid & 7;  // 8 threads per token
    const size_t tok = (size_t)(blk * BM + tb);
    const int idx = chosen[tb];
    float sq = 0.f;
    if (idx >= 0) {
      const float4* cp = (const float4*)(cb + (size_t)idx * DIM);
      const float4* rp = (const float4*)(rin + tok * DIM);
      const float4* xp = (const float4*)(x + tok * DIM);
      float4* op = (float4*)(resid + tok * DIM);
#pragma unroll 4
      for (int kk = 0; kk < 16; ++kk) {
        const int d4 = part + kk * 8;
        const float4 r = rp[d4], c4 = cp[d4];
        float4 rn;
        rn.x = r.x - c4.x; rn.y = r.y - c4.y; rn.z = r.z - c4.z; rn.w = r.w - c4.w;
        sq += rn.x * rn.x + rn.y * rn.y + rn.z * rn.z + rn.w * rn.w;
        if (LAST) {
          const float4 xv = xp[d4];
          float4 qv;
          qv.x = xv.x - rn.x; qv.y = xv.y - rn.y; qv.z = xv.z - rn.z; qv.w = xv.w - rn.w;
          op[d4] = qv;
        } else {
          op[d4] = rn;
        }
      }
    }
#pragma unroll
    for (int off = 32; off; off >>= 1) sq += __shfl_down(sq, off);
    if (lane == 0) atomicAdd(commit, sq);
  }
}

// ===================== old fp32 path (fallback if ws too small) =============
template <bool FIRST, bool LAST>
__global__ __launch_bounds__(512, 2) void level_kernel(
    const float* __restrict__ x, float* __restrict__ resid,
    const float* __restrict__ cb, const float* __restrict__ cnorm,
    float* __restrict__ out_idx, float* __restrict__ counts,
    float* __restrict__ commit, int* __restrict__ rcnt,
    int* __restrict__ rlist, int qlev) {
  __shared__ float Rs[DC][BM + 4];
  __shared__ float Cs[DC][KCODE + 4];
  __shared__ int chosen[BM];

  const int tid = threadIdx.x;
  const int lane = tid & 63;
  const int ty = tid >> 6;
  const int tx = lane;
  const int blk = blockIdx.x;
  const float* rin = FIRST ? x : resid;

  float acc[8][16];
#pragma unroll
  for (int j = 0; j < 8; ++j)
#pragma unroll
    for (int g = 0; g < 16; ++g) acc[j][g] = 0.f;

  float4 pc[4];
  float4 pr;
  {
#pragma unroll
    for (int u = 0; u < 4; ++u) {
      const int f4 = tid + u * 512;
      const int code = f4 >> 1, d4 = f4 & 1;
      pc[u] = *(const float4*)(cb + (size_t)code * DIM + d4 * 4);
    }
    if (tid < 128) {
      const int tok = tid >> 1, d4 = tid & 1;
      pr = *(const float4*)(rin + (size_t)(blk * BM + tok) * DIM + d4 * 4);
    }
  }

  for (int dc = 0; dc < NCH; ++dc) {
    __syncthreads();
#pragma unroll
    for (int u = 0; u < 4; ++u) {
      const int f4 = tid + u * 512;
      const int code = f4 >> 1, d4 = f4 & 1;
      Cs[d4 * 4 + 0][code] = pc[u].x;
      Cs[d4 * 4 + 1][code] = pc[u].y;
      Cs[d4 * 4 + 2][code] = pc[u].z;
      Cs[d4 * 4 + 3][code] = pc[u].w;
    }
    if (tid < 128) {
      const int tok = tid >> 1, d4 = tid & 1;
      Rs[d4 * 4 + 0][tok] = pr.x;
      Rs[d4 * 4 + 1][tok] = pr.y;
      Rs[d4 * 4 + 2][tok] = pr.z;
      Rs[d4 * 4 + 3][tok] = pr.w;
    }
    if (dc + 1 < NCH) {
      const int doff = (dc + 1) * DC;
#pragma unroll
      for (int u = 0; u < 4; ++u) {
        const int f4 = tid + u * 512;
        const int code = f4 >> 1, d4 = f4 & 1;
        pc[u] = *(const float4*)(cb + (size_t)code * DIM + doff + d4 * 4);
      }
      if (tid < 128) {
        const int tok = tid >> 1, d4 = tid & 1;
        pr = *(const float4*)(rin + (size_t)(blk * BM + tok) * DIM + doff + d4 * 4);
      }
    }
    __syncthreads();
#pragma unroll
    for (int d = 0; d < DC; ++d) {
      const float4 ra = *(const float4*)&Rs[d][ty * 8];
      const float4 rb = *(const float4*)&Rs[d][ty * 8 + 4];
#pragma unroll
      for (int q = 0; q < 4; ++q) {
        const float4 cv = *(const float4*)&Cs[d][q * 256 + tx * 4];
        const float c0 = cv.x, c1 = cv.y, c2 = cv.z, c3 = cv.w;
        acc[0][q * 4 + 0] = fmaf(ra.x, c0, acc[0][q * 4 + 0]);
        acc[0][q * 4 + 1] = fmaf(ra.x, c1, acc[0][q * 4 + 1]);
        acc[0][q * 4 + 2] = fmaf(ra.x, c2, acc[0][q * 4 + 2]);
        acc[0][q * 4 + 3] = fmaf(ra.x, c3, acc[0][q * 4 + 3]);
        acc[1][q * 4 + 0] = fmaf(ra.y, c0, acc[1][q * 4 + 0]);
        acc[1][q * 4 + 1] = fmaf(ra.y, c1, acc[1][q * 4 + 1]);
        acc[1][q * 4 + 2] = fmaf(ra.y, c2, acc[1][q * 4 + 2]);
        acc[1][q * 4 + 3] = fmaf(ra.y, c3, acc[1][q * 4 + 3]);
        acc[2][q * 4 + 0] = fmaf(ra.z, c0, acc[2][q * 4 + 0]);
        acc[2][q * 4 + 1] = fmaf(ra.z, c1, acc[2][q * 4 + 1]);
        acc[2][q * 4 + 2] = fmaf(ra.z, c2, acc[2][q * 4 + 2]);
        acc[2][q * 4 + 3] = fmaf(ra.z, c3, acc[2][q * 4 + 3]);
        acc[3][q * 4 + 0] = fmaf(ra.w, c0, acc[3][q * 4 + 0]);
        acc[3][q * 4 + 1] = fmaf(ra.w, c1, acc[3][q * 4 + 1]);
        acc[3][q * 4 + 2] = fmaf(ra.w, c2, acc[3][q * 4 + 2]);
        acc[3][q * 4 + 3] = fmaf(ra.w, c3, acc[3][q * 4 + 3]);
        acc[4][q * 4 + 0] = fmaf(rb.x, c0, acc[4][q * 4 + 0]);
        acc[4][q * 4 + 1] = fmaf(rb.x, c1, acc[4][q * 4 + 1]);
        acc[4][q * 4 + 2] = fmaf(rb.x, c2, acc[4][q * 4 + 2]);
        acc[4][q * 4 + 3] = fmaf(rb.x, c3, acc[4][q * 4 + 3]);
        acc[5][q * 4 + 0] = fmaf(rb.y, c0, acc[5][q * 4 + 0]);
        acc[5][q * 4 + 1] = fmaf(rb.y, c1, acc[5][q * 4 + 1]);
        acc[5][q * 4 + 2] = fmaf(rb.y, c2, acc[5][q * 4 + 2]);
        acc[5][q * 4 + 3] = fmaf(rb.y, c3, acc[5][q * 4 + 3]);
        acc[6][q * 4 + 0] = fmaf(rb.z, c0, acc[6][q * 4 + 0]);
        acc[6][q * 4 + 1] = fmaf(rb.z, c1, acc[6][q * 4 + 1]);
        acc[6][q * 4 + 2] = fmaf(rb.z, c2, acc[6][q * 4 + 2]);
        acc[6][q * 4 + 3] = fmaf(rb.z, c3, acc[6][q * 4 + 3]);
        acc[7][q * 4 + 0] = fmaf(rb.w, c0, acc[7][q * 4 + 0]);
        acc[7][q * 4 + 1] = fmaf(rb.w, c1, acc[7][q * 4 + 1]);
        acc[7][q * 4 + 2] = fmaf(rb.w, c2, acc[7][q * 4 + 2]);
        acc[7][q * 4 + 3] = fmaf(rb.w, c3, acc[7][q * 4 + 3]);
      }
    }
  }

  float v1[8], v2[8];
  int i1[8], i2[8];
#pragma unroll
  for (int j = 0; j < 8; ++j) { v1[j] = v2[j] = 3.4e38f; i1[j] = i2[j] = KCODE; }
#pragma unroll
  for (int g = 0; g < 16; ++g) {
    const int c = (g >> 2) * 256 + tx * 4 + (g & 3);
    const float cn = cnorm[c];
#pragma unroll
    for (int j = 0; j < 8; ++j) {
      const float dist = fmaf(-2.f, acc[j][g], cn);
      if (lt2(dist, c, v1[j], i1[j])) {
        v2[j] = v1[j]; i2[j] = i1[j]; v1[j] = dist; i1[j] = c;
      } else if (lt2(dist, c, v2[j], i2[j])) {
        v2[j] = dist; i2[j] = c;
      }
    }
  }
#pragma unroll
  for (int off = 1; off < 64; off <<= 1) {
#pragma unroll
    for (int j = 0; j < 8; ++j) {
      const float w1 = __shfl_xor(v1[j], off);
      const int j1 = __shfl_xor(i1[j], off);
      const float w2 = __shfl_xor(v2[j], off);
      const int j2 = __shfl_xor(i2[j], off);
      if (lt2(w1, j1, v1[j], i1[j])) {
        if (lt2(v1[j], i1[j], w2, j2)) { v2[j] = v1[j]; i2[j] = i1[j]; }
        else { v2[j] = w2; i2[j] = j2; }
        v1[j] = w1; i1[j] = j1;
      } else {
        if (lt2(w1, j1, v2[j], i2[j])) { v2[j] = w1; i2[j] = j1; }
      }
    }
  }
  if (lane < 8) {
    const int tb = ty * 8 + lane;
    const float V1 = v1[lane], V2 = v2[lane];
    const int I1 = i1[lane];
    if (V2 - V1 < TAU) {
      const int pos = atomicAdd(rcnt, 1);
      rlist[pos] = blk * BM + tb;
      chosen[tb] = -1;
    } else {
      chosen[tb] = I1;
      out_idx[(size_t)(blk * BM + tb) * QLV + qlev] = (float)I1;
      atomicAdd(&counts[I1], 1.0f);
    }
  }
  __syncthreads();
  {
    const int tb = tid >> 3, part = tid & 7;
    const size_t tok = (size_t)(blk * BM + tb);
    const int idx = chosen[tb];
    float sq = 0.f;
    if (idx >= 0) {
      const float4* cp = (const float4*)(cb + (size_t)idx * DIM);
      const float4* rp = (const float4*)(rin + tok * DIM);
      const float4* xp = (const float4*)(x + tok * DIM);
      float4* op = (float4*)(resid + tok * DIM);
#pragma unroll 4
      for (int kk = 0; kk < 16; ++kk) {
        const int d4 = part + kk * 8;
        const float4 r = rp[d4], c4 = cp[d4];
        float4 rn;
        rn.x = r.x - c4.x; rn.y = r.y - c4.y; rn.z = r.z - c4.z; rn.w = r.w - c4.w;
        sq += rn.x * rn.x + rn.y * rn.y + rn.z * rn.z + rn.w * rn.w;
        if (LAST) {
          const float4 xv = xp[d4];
          float4 qv;
          qv.x = xv.x - rn.x; qv.y = xv.y - rn.y; qv.z = xv.z - rn.z; qv.w = xv.w - rn.w;
          op[d4] = qv;
        } else {
          op[d4] = rn;
        }
      }
    }
#pragma unroll
    for (int off = 32; off; off >>= 1) sq += __shfl_down(sq, off);
    if (lane == 0) atomicAdd(commit, sq);
  }
}

// Near-tie finalization replicating numpy-fp32 semantics exactly (PROVEN r4).
template <bool LAST>
__global__ __launch_bounds__(256) void rescue_np(
    const float* __restrict__ x, const float* __restrict__ rin,
    float* __restrict__ resid, const float* __restrict__ cbq,
    const float* __restrict__ cnq, float* __restrict__ out_idx,
    float* __restrict__ counts, float* __restrict__ commit,
    const int* __restrict__ rcnt, const int* __restrict__ rlist, int qlev) {
  __shared__ float rsh[DIM];
  __shared__ float sA;
  __shared__ float wv[4];
  __shared__ int wi[4];
  __shared__ int bestk_s;
  const int tid = threadIdx.x;
  const int n = rcnt[0];
  for (int it = blockIdx.x; it < n; it += gridDim.x) {
    const int t = rlist[it];
    rsh[tid] = rin[(size_t)t * DIM + tid];
    rsh[256 + tid] = rin[(size_t)t * DIM + 256 + tid];
    __syncthreads();
    if (tid == 0) sA = np_sum512_sq(rsh);
    __syncthreads();
    const float A = sA;
    float bv = 3.4e38f;
    int bi = KCODE;
    for (int kk = 0; kk < 4; ++kk) {
      const int k = tid * 4 + kk;
      const float d = np_dist(A, rsh, cbq + (size_t)k * DIM, cnq[k]);
      if (d < bv) { bv = d; bi = k; }
    }
#pragma unroll
    for (int off = 32; off; off >>= 1) {
      const float ov = __shfl_down(bv, off);
      const int oi = __shfl_down(bi, off);
      if (ov < bv || (ov == bv && oi < bi)) { bv = ov; bi = oi; }
    }
    if ((tid & 63) == 0) { wv[tid >> 6] = bv; wi[tid >> 6] = bi; }
    __syncthreads();
    if (tid == 0) {
      float V = wv[0]; int I = wi[0];
#pragma unroll
      for (int w = 1; w < 4; ++w)
        if (wv[w] < V || (wv[w] == V && wi[w] < I)) { V = wv[w]; I = wi[w]; }
      bestk_s = I;
      out_idx[(size_t)t * QLV + qlev] = (float)I;
      atomicAdd(&counts[I], 1.0f);
    }
    __syncthreads();
    const float* crow = cbq + (size_t)bestk_s * DIM;
    float sq;
    {
      const int d0 = tid, d1 = tid + 256;
      const float rn0 = rsh[d0] - crow[d0];
      const float rn1 = rsh[d1] - crow[d1];
      sq = rn0 * rn0 + rn1 * rn1;
      if (LAST) {
        resid[(size_t)t * DIM + d0] = x[(size_t)t * DIM + d0] - rn0;
        resid[(size_t)t * DIM + d1] = x[(size_t)t * DIM + d1] - rn1;
      } else {
        resid[(size_t)t * DIM + d0] = rn0;
        resid[(size_t)t * DIM + d1] = rn1;
      }
    }
#pragma unroll
    for (int off = 32; off; off >>= 1) sq += __shfl_down(sq, off);
    if ((tid & 63) == 0) wv[tid >> 6] = sq;
    __syncthreads();
    if (tid == 0)
      atomicAdd(commit, wv[0] + wv[1] + wv[2] + wv[3]);
    __syncthreads();
  }
}

__global__ __launch_bounds__(256) void finalize_scalars(const float* __restrict__ counts,
                                                        const float* __restrict__ commit,
                                                        float* __restrict__ out2) {
  const int tid = threadIdx.x;
  __shared__ float sh[4];
  __shared__ float perp_acc;
  if (tid == 0) perp_acc = 0.f;
  __syncthreads();
  for (int q = 0; q < QLV; ++q) {
    float h = 0.f;
    for (int k = tid; k < KCODE; k += 256) {
      const float p = counts[q * KCODE + k] * (1.0f / (float)NTOK);
      h += p * logf(p + 1e-10f);
    }
#pragma unroll
    for (int off = 32; off; off >>= 1) h += __shfl_down(h, off);
    if ((tid & 63) == 0) sh[tid >> 6] = h;
    __syncthreads();
    if (tid == 0) {
      const float H = sh[0] + sh[1] + sh[2] + sh[3];
      perp_acc += expf(-H);
    }
    __syncthreads();
  }
  if (tid == 0) {
    float closs = 0.f;
    for (int q = 0; q < QLV; ++q) closs += commit[q];
    out2[0] = closs * (0.25f / ((float)NTOK * (float)DIM));
    out2[1] = perp_acc * (1.0f / (float)QLV);
  }
}

extern "C" void kernel_launch(void* const* d_in, const int* in_sizes, int n_in,
                              void* d_out, int out_size, void* d_ws, size_t ws_size,
                              hipStream_t stream) {
  const float* x = (const float*)d_in[0];
  const float* cb = (const float*)d_in[1];
  float* out = (float*)d_out;
  float* ws = (float*)d_ws;

  float* resid = out;
  float* oidx = out + (size_t)NTOK * DIM;
  float* scal = oidx + (size_t)NTOK * QLV;
  float* counts = ws;
  float* commit = ws + QLV * KCODE;
  int* rcnt = (int*)(ws + QLV * KCODE + QLV);
  float* cnorm = ws + QLV * KCODE + 512;
  int* rlist = (int*)(ws + QLV * KCODE + 512 + QLV * KCODE);
  unsigned short* cbsplit = (unsigned short*)(ws + CBSPLIT_FLOAT_OFF);

  const size_t need = (size_t)CBSPLIT_FLOAT_OFF * 4 + (size_t)QLV * NCK * CHUNKB;
  const bool use_mfma = ws_size >= need;

  hipLaunchKernelGGL(zero_ws, dim3(32), dim3(256), 0, stream, ws);
  hipLaunchKernelGGL(cnorm_np_kernel, dim3((QLV * KCODE) / 256), dim3(256), 0, stream,
                     cb, cnorm);
  if (use_mfma)
    hipLaunchKernelGGL(split_cb_kernel, dim3((QLV * KCODE * DIM / 4) / 256), dim3(256), 0,
                       stream, cb, cbsplit);

  for (int q = 0; q < QLV; ++q) {
    const float* cbq = cb + (size_t)q * KCODE * DIM;
    const float* cnq = cnorm + q * KCODE;
    float* ctq = counts + q * KCODE;
    float* cmq = commit + q;
    int* rcq = rcnt + q;
    const float* rin = (q == 0) ? x : resid;
    if (use_mfma) {
      const unsigned short* csq = cbsplit + (size_t)q * (NCK * CHUNKB / 2);
      if (q == 0)
        hipLaunchKernelGGL((level_mfma<true, false>), dim3(NTOK / BM), dim3(512), 0, stream,
                           x, resid, cbq, csq, cnq, oidx, ctq, cmq, rcq, rlist, q);
      else if (q == QLV - 1)
        hipLaunchKernelGGL((level_mfma<false, true>), dim3(NTOK / BM), dim3(512), 0, stream,
                           x, resid, cbq, csq, cnq, oidx, ctq, cmq, rcq, rlist, q);
      else
        hipLaunchKernelGGL((level_mfma<false, false>), dim3(NTOK / BM), dim3(512), 0, stream,
                           x, resid, cbq, csq, cnq, oidx, ctq, cmq, rcq, rlist, q);
    } else {
      if (q == 0)
        hipLaunchKernelGGL((level_kernel<true, false>), dim3(NTOK / BM), dim3(512), 0, stream,
                           x, resid, cbq, cnq, oidx, ctq, cmq, rcq, rlist, q);
      else if (q == QLV - 1)
        hipLaunchKernelGGL((level_kernel<false, true>), dim3(NTOK / BM), dim3(512), 0, stream,
                           x, resid, cbq, cnq, oidx, ctq, cmq, rcq, rlist, q);
      else
        hipLaunchKernelGGL((level_kernel<false, false>), dim3(NTOK / BM), dim3(512), 0, stream,
                           x, resid, cbq, cnq, oidx, ctq, cmq, rcq, rlist, q);
    }
    if (q == QLV - 1)
      hipLaunchKernelGGL((rescue_np<true>), dim3(256), dim3(256), 0, stream,
                         x, rin, resid, cbq, cnq, oidx, ctq, cmq, rcq, rlist, q);
    else
      hipLaunchKernelGGL((rescue_np<false>), dim3(256), dim3(256), 0, stream,
                         x, rin, resid, cbq, cnq, oidx, ctq, cmq, rcq, rlist, q);
  }
  hipLaunchKernelGGL(finalize_scalars, dim3(1), dim3(256), 0, stream, counts, commit, scal);
}

// Round 2
// 1165.962 us; speedup vs baseline: 2.2934x; 1.3259x over previous
//
#include <hip/hip_runtime.h>
#include <math.h>

#define NTOK 16384
#define DIM 512
#define QLV 8
#define KCODE 1024
#define BM 64
#define DC 8
#define NCH (DIM / DC)  // 64 d-chunks (old path)
#define TAU 1e-3f       // bf16x3 MFMA adds <=2.5e-4 abs error; TAU >= 2*eps

// ---- MFMA path constants ----
#define NCK 16          // 16 chunks of 32 d
#define CHUNKB 131072   // bytes per chunk in split-cb: 2 halves x (hi+lo) x 512 codes x 64 B
#define CBSPLIT_FLOAT_OFF 65536  // float offset of split-cb region inside ws (256 KB in)
#define RCAP 16         // per-token rescue candidate cap

typedef __attribute__((ext_vector_type(4))) float f32x4;
typedef __attribute__((ext_vector_type(8))) short bf16x8;

__global__ __launch_bounds__(256) void zero_ws(float* ws) {
  int i = blockIdx.x * 256 + threadIdx.x;
  for (int k = i; k < QLV * KCODE + 2 * QLV; k += gridDim.x * 256) ws[k] = 0.f;
}

// ---- numpy float32 replication helpers (PROVEN in round 4 — do not touch) --
__device__ __forceinline__ float np_blk128_sq(const float* __restrict__ x) {
#pragma clang fp contract(off)
  float L[16];
#pragma unroll
  for (int j = 0; j < 16; ++j) {
    const float a0 = x[j] * x[j];
    const float a1 = x[16 + j] * x[16 + j];
    const float a2 = x[32 + j] * x[32 + j];
    const float a3 = x[48 + j] * x[48 + j];
    const float a4 = x[64 + j] * x[64 + j];
    const float a5 = x[80 + j] * x[80 + j];
    const float a6 = x[96 + j] * x[96 + j];
    const float a7 = x[112 + j] * x[112 + j];
    L[j] = ((a0 + a1) + (a2 + a3)) + ((a4 + a5) + (a6 + a7));
  }
  float T3[8];
#pragma unroll
  for (int i = 0; i < 8; ++i) T3[i] = L[i] + L[i + 8];
  float T6[4];
#pragma unroll
  for (int j = 0; j < 4; ++j) T6[j] = T3[j] + T3[j + 4];
  return (T6[0] + T6[2]) + (T6[1] + T6[3]);
}

__device__ __forceinline__ float np_sum512_sq(const float* __restrict__ x) {
#pragma clang fp contract(off)
  const float p0 = np_blk128_sq(x);
  const float p1 = np_blk128_sq(x + 128);
  const float p2 = np_blk128_sq(x + 256);
  const float p3 = np_blk128_sq(x + 384);
  const float s01 = p0 + p1;
  const float s23 = p2 + p3;
  return s01 + s23;
}

__device__ __forceinline__ float np_dist(float A, const float* __restrict__ r,
                                         const float* __restrict__ c, float cn) {
#pragma clang fp contract(off)
  float b1 = 0.f;
#pragma unroll 8
  for (int d = 0; d < 384; ++d) b1 = __builtin_fmaf(r[d], c[d], b1);
  float b2 = 0.f;
#pragma unroll 8
  for (int d = 384; d < 512; ++d) b2 = __builtin_fmaf(r[d], c[d], b2);
  const float B = b1 + b2;
  const float t1 = 2.0f * B;
  const float t2 = A - t1;
  return t2 + cn;
}
// ---------------------------------------------------------------------------

__global__ __launch_bounds__(256) void cnorm_np_kernel(const float* __restrict__ cb,
                                                       float* __restrict__ cn) {
  const int row = blockIdx.x * 256 + threadIdx.x;  // [0, Q*K)
  cn[row] = np_sum512_sq(cb + (size_t)row * DIM);
}

// lexicographic (val, idx) less-than
__device__ __forceinline__ bool lt2(float a, int ia, float b, int ib) {
  return a < b || (a == b && ia < ib);
}

// ---- bf16 split helpers (RTNE) ----
__device__ __forceinline__ unsigned short bf16_rtne(float x) {
  unsigned u = __builtin_bit_cast(unsigned, x);
  u += 0x7FFFu + ((u >> 16) & 1u);
  return (unsigned short)(u >> 16);
}
__device__ __forceinline__ float bf16_tof(unsigned short h) {
  unsigned u = (unsigned)h << 16;
  return __builtin_bit_cast(float, u);
}
__device__ __forceinline__ void split2(float x, unsigned short& h, unsigned short& l) {
  h = bf16_rtne(x);
  l = bf16_rtne(x - bf16_tof(h));
}

__device__ __forceinline__ void gload16(const void* g, void* l) {
  __builtin_amdgcn_global_load_lds(
      (const __attribute__((address_space(1))) unsigned int*)g,
      (__attribute__((address_space(3))) unsigned int*)l, 16, 0, 0);
}

// One-time: split fp32 codebooks into pre-swizzled bf16 hi/lo tiles in ws.
__global__ __launch_bounds__(256) void split_cb_kernel(const float* __restrict__ cb,
                                                       unsigned short* __restrict__ dst) {
  const int f = blockIdx.x * 256 + threadIdx.x;  // float4 index, 2^20 total
  const int d4 = f & 127;
  const int c = (f >> 7) & 1023;
  const int q = f >> 17;
  const float4 v = *(const float4*)(cb + (size_t)f * 4);
  const int d0 = d4 * 4;
  const int dc = d0 >> 5;
  const int e = d0 & 31;
  const int kb = e >> 3;
  const int e7 = e & 7;  // 0 or 4
  const int half = c >> 9, cl = c & 511;
  const int slot = kb ^ ((cl >> 1) & 3);
  const size_t base = (size_t)(q * NCK + dc) * CHUNKB + (size_t)half * 65536;
  const size_t off = base + (size_t)cl * 64 + (size_t)slot * 16 + (size_t)e7 * 2;
  unsigned short h0, l0, h1, l1, h2, l2, h3, l3;
  split2(v.x, h0, l0);
  split2(v.y, h1, l1);
  split2(v.z, h2, l2);
  split2(v.w, h3, l3);
  uint2 hv, lv;
  hv.x = (unsigned)h0 | ((unsigned)h1 << 16);
  hv.y = (unsigned)h2 | ((unsigned)h3 << 16);
  lv.x = (unsigned)l0 | ((unsigned)l1 << 16);
  lv.y = (unsigned)l2 | ((unsigned)l3 << 16);
  char* db = (char*)dst;
  *(uint2*)(db + off) = hv;            // hi plane
  *(uint2*)(db + off + 32768) = lv;    // lo plane
}

// ===================== MFMA level kernel =====================
// Block: 64 tokens x 1024 codes, 512 threads (8 waves).
// Raw-barrier counted-vmcnt schedule (T3/T4) + setprio (T5):
//   phase A: vmcnt(8); bar; [pA load] ds_read A+B(H0); lgkm(0); sbar0; MFMA*48; bar; issue H0(dc+1)
//   phase B: vmcnt(9); bar; split A(dc+1)->LDS; ds_read B(H1); lgkm(0); sbar0; MFMA*48; bar; issue H1(dc+1)
// Wrap-around issues at dc=15 keep vmcnt counts uniform (strays drained by epilogue __syncthreads).
template <bool FIRST, bool LAST>
__global__ __launch_bounds__(512, 2) void level_mfma(
    const float* __restrict__ x, float* __restrict__ resid,
    const float* __restrict__ cb, const unsigned short* __restrict__ cbsplit,
    const float* __restrict__ cnorm, float* __restrict__ out_idx,
    float* __restrict__ counts, float* __restrict__ commit, int* __restrict__ rcnt,
    int* __restrict__ rlist, int* __restrict__ cand_cnt, int* __restrict__ cand,
    int have_cand, int qlev) {
  __shared__ __align__(16) unsigned char Bs[131072];       // [half][hl][512][64B]
  __shared__ __align__(16) unsigned char As[16384];        // [buf][hl][64][64B]
  __shared__ __align__(16) float foldb[64][8][4];
  __shared__ int chosen[64];
  __shared__ float tieV1[64];
  __shared__ int ccnt[64];

  const int tid = threadIdx.x;
  const int lane = tid & 63;
  const int w = tid >> 6;
  const int col = lane & 15;
  const int kb = lane >> 4;
  const int blk = blockIdx.x;
  const float* rin = FIRST ? x : resid;
  const char* csp = (const char*)cbsplit;
  const size_t wl = (size_t)w * 8192 + (size_t)lane * 16;  // per-wave B stage src offset

  // A-staging geometry: thread -> (row, 4 d's)
  const int arow = tid >> 3;
  const int ae0 = (tid & 7) * 4;
  const int akb = ae0 >> 3;
  const int aslot = akb ^ ((arow >> 1) & 3);
  const size_t abyte = (size_t)arow * 64 + (size_t)aslot * 16 + (size_t)(ae0 & 7) * 2;
  const float* aglob = rin + (size_t)(blk * BM + arow) * DIM + ae0;

  f32x4 acc[2][4][4];
#pragma unroll
  for (int h = 0; h < 2; ++h)
#pragma unroll
    for (int j = 0; j < 4; ++j)
#pragma unroll
      for (int tf = 0; tf < 4; ++tf) acc[h][j][tf] = (f32x4){0.f, 0.f, 0.f, 0.f};

  // ---- prologue: A(0) split->LDS buf0; issue H0(0), H1(0) ----
  {
    const float4 pA = *(const float4*)aglob;
    unsigned short h0, l0, h1, l1, h2, l2, h3, l3;
    split2(pA.x, h0, l0);
    split2(pA.y, h1, l1);
    split2(pA.z, h2, l2);
    split2(pA.w, h3, l3);
    uint2 hv, lv;
    hv.x = (unsigned)h0 | ((unsigned)h1 << 16);
    hv.y = (unsigned)h2 | ((unsigned)h3 << 16);
    lv.x = (unsigned)l0 | ((unsigned)l1 << 16);
    lv.y = (unsigned)l2 | ((unsigned)l3 << 16);
    *(uint2*)&As[abyte] = hv;
    *(uint2*)&As[4096 + abyte] = lv;
  }
  {
    const char* s = csp + wl;
    unsigned char* d = &Bs[(size_t)w * 8192];
#pragma unroll
    for (int i = 0; i < 8; ++i) gload16(s + i * 1024, d + i * 1024);
  }
  {
    const char* s = csp + 65536 + wl;
    unsigned char* d = &Bs[65536 + (size_t)w * 8192];
#pragma unroll
    for (int i = 0; i < 8; ++i) gload16(s + i * 1024, d + i * 1024);
  }
  asm volatile("s_waitcnt lgkmcnt(0)" ::: "memory");  // A(0) ds_writes drained

  for (int dc = 0; dc < NCK; ++dc) {
    const int dn = (dc + 1) & (NCK - 1);
    const int abuf = dc & 1;
    const char* srcN = csp + (size_t)dn * CHUNKB;

    // ================= phase A: compute half0 =================
    asm volatile("s_waitcnt vmcnt(8)" ::: "memory");  // my H0(dc) landed (H1(dc) in flight)
    asm volatile("s_barrier" ::: "memory");           // all waves' H0(dc) + A(dc) visible
    const float4 pAn = *(const float4*)(aglob + dn * 32);  // A for next chunk

    bf16x8 ah[4], al[4];
#pragma unroll
    for (int tf = 0; tf < 4; ++tf) {
      const int row = tf * 16 + col;
      const size_t slot16 = (size_t)((kb ^ ((row >> 1) & 3)) * 16);
      const size_t ab = (size_t)abuf * 8192 + (size_t)row * 64 + slot16;
      ah[tf] = *(const bf16x8*)&As[ab];
      al[tf] = *(const bf16x8*)&As[ab + 4096];
    }
    bf16x8 b0h[4], b0l[4];
#pragma unroll
    for (int j = 0; j < 4; ++j) {
      const int cl = (w + 8 * j) * 16 + col;
      const size_t bb = (size_t)cl * 64 + (size_t)((kb ^ ((cl >> 1) & 3)) * 16);
      b0h[j] = *(const bf16x8*)&Bs[bb];
      b0l[j] = *(const bf16x8*)&Bs[32768 + bb];
    }
    asm volatile("s_waitcnt lgkmcnt(0)" ::: "memory");
    __builtin_amdgcn_sched_barrier(0);
    __builtin_amdgcn_s_setprio(1);
#pragma unroll
    for (int j = 0; j < 4; ++j)
#pragma unroll
      for (int tf = 0; tf < 4; ++tf) {
        acc[0][j][tf] = __builtin_amdgcn_mfma_f32_16x16x32_bf16(ah[tf], b0h[j], acc[0][j][tf], 0, 0, 0);
        acc[0][j][tf] = __builtin_amdgcn_mfma_f32_16x16x32_bf16(al[tf], b0h[j], acc[0][j][tf], 0, 0, 0);
        acc[0][j][tf] = __builtin_amdgcn_mfma_f32_16x16x32_bf16(ah[tf], b0l[j], acc[0][j][tf], 0, 0, 0);
      }
    __builtin_amdgcn_s_setprio(0);
    asm volatile("s_barrier" ::: "memory");           // everyone done reading H0 region
    {
      const char* s = srcN + wl;
      unsigned char* d = &Bs[(size_t)w * 8192];
#pragma unroll
      for (int i = 0; i < 8; ++i) gload16(s + i * 1024, d + i * 1024);  // H0(dc+1)
    }

    // ================= phase B: compute half1 =================
    asm volatile("s_waitcnt vmcnt(9)" ::: "memory");  // my H1(dc) landed (pA + H0(dc+1) in flight)
    asm volatile("s_barrier" ::: "memory");           // all waves' H1(dc) visible
    {  // split & stage A(dc+1) into the other A buffer (overlaps with MFMA below)
      unsigned short h0, l0, h1, l1, h2, l2, h3, l3;
      split2(pAn.x, h0, l0);
      split2(pAn.y, h1, l1);
      split2(pAn.z, h2, l2);
      split2(pAn.w, h3, l3);
      uint2 hv, lv;
      hv.x = (unsigned)h0 | ((unsigned)h1 << 16);
      hv.y = (unsigned)h2 | ((unsigned)h3 << 16);
      lv.x = (unsigned)l0 | ((unsigned)l1 << 16);
      lv.y = (unsigned)l2 | ((unsigned)l3 << 16);
      const size_t ab0 = (size_t)(abuf ^ 1) * 8192 + abyte;
      *(uint2*)&As[ab0] = hv;
      *(uint2*)&As[ab0 + 4096] = lv;
    }
    bf16x8 b1h[4], b1l[4];
#pragma unroll
    for (int j = 0; j < 4; ++j) {
      const int cl = (w + 8 * j) * 16 + col;
      const size_t bb = (size_t)cl * 64 + (size_t)((kb ^ ((cl >> 1) & 3)) * 16);
      b1h[j] = *(const bf16x8*)&Bs[65536 + bb];
      b1l[j] = *(const bf16x8*)&Bs[65536 + 32768 + bb];
    }
    asm volatile("s_waitcnt lgkmcnt(0)" ::: "memory");  // A writes + B reads drained
    __builtin_amdgcn_sched_barrier(0);
    __builtin_amdgcn_s_setprio(1);
#pragma unroll
    for (int j = 0; j < 4; ++j)
#pragma unroll
      for (int tf = 0; tf < 4; ++tf) {
        acc[1][j][tf] = __builtin_amdgcn_mfma_f32_16x16x32_bf16(ah[tf], b1h[j], acc[1][j][tf], 0, 0, 0);
        acc[1][j][tf] = __builtin_amdgcn_mfma_f32_16x16x32_bf16(al[tf], b1h[j], acc[1][j][tf], 0, 0, 0);
        acc[1][j][tf] = __builtin_amdgcn_mfma_f32_16x16x32_bf16(ah[tf], b1l[j], acc[1][j][tf], 0, 0, 0);
      }
    __builtin_amdgcn_s_setprio(0);
    asm volatile("s_barrier" ::: "memory");           // everyone done reading H1 region
    {
      const char* s = srcN + 65536 + wl;
      unsigned char* d = &Bs[65536 + (size_t)w * 8192];
#pragma unroll
      for (int i = 0; i < 8; ++i) gload16(s + i * 1024, d + i * 1024);  // H1(dc+1)
    }
  }
  __syncthreads();  // real barrier: drains stray wrap-around loads before epilogue

  // ---- epilogue: fold top-2 per token over this wave's 128 codes ----
  float cnv[2][4];
#pragma unroll
  for (int h = 0; h < 2; ++h)
#pragma unroll
    for (int j = 0; j < 4; ++j) cnv[h][j] = cnorm[(h * 32 + w + 8 * j) * 16 + col];

#pragma unroll
  for (int tf = 0; tf < 4; ++tf) {
#pragma unroll
    for (int r = 0; r < 4; ++r) {
      float b1 = 3.4e38f, b2 = 3.4e38f;
      int x1 = KCODE, x2 = KCODE;
#pragma unroll
      for (int h = 0; h < 2; ++h)
#pragma unroll
        for (int j = 0; j < 4; ++j) {
          const int c = (h * 32 + w + 8 * j) * 16 + col;
          const float dist = fmaf(-2.f, acc[h][j][tf][r], cnv[h][j]);
          if (lt2(dist, c, b1, x1)) {
            b2 = b1; x2 = x1; b1 = dist; x1 = c;
          } else if (lt2(dist, c, b2, x2)) {
            b2 = dist; x2 = c;
          }
        }
      // butterfly across the 16 lanes of this col-group
#pragma unroll
      for (int off = 1; off < 16; off <<= 1) {
        const float w1 = __shfl_xor(b1, off);
        const int j1 = __shfl_xor(x1, off);
        const float w2 = __shfl_xor(b2, off);
        const int j2 = __shfl_xor(x2, off);
        if (lt2(w1, j1, b1, x1)) {
          if (lt2(b1, x1, w2, j2)) { b2 = b1; x2 = x1; }
          else { b2 = w2; x2 = j2; }
          b1 = w1; x1 = j1;
        } else if (lt2(w1, j1, b2, x2)) {
          b2 = w1; x2 = j1;
        }
      }
      if (col == 0) {
        const int t = tf * 16 + (lane >> 4) * 4 + r;
        float4 fv;
        fv.x = b1; fv.y = __int_as_float(x1); fv.z = b2; fv.w = __int_as_float(x2);
        *(float4*)&foldb[t][w][0] = fv;
      }
    }
  }
  __syncthreads();

  // ---- merge 8 wave-results per token; gap test; decide/rescue ----
  if (tid < 64) {
    float V1 = 3.4e38f, V2 = 3.4e38f;
    int I1 = KCODE, I2 = KCODE;
#pragma unroll
    for (int ww = 0; ww < 8; ++ww) {
      const float4 e = *(const float4*)&foldb[tid][ww][0];
      const float a1 = e.x, a2 = e.z;
      const int a1i = __float_as_int(e.y), a2i = __float_as_int(e.w);
      if (lt2(a1, a1i, V1, I1)) {
        if (lt2(V1, I1, a2, a2i)) { V2 = V1; I2 = I1; }
        else { V2 = a2; I2 = a2i; }
        V1 = a1; I1 = a1i;
      } else if (lt2(a1, a1i, V2, I2)) {
        V2 = a1; I2 = a1i;
      }
    }
    ccnt[tid] = 0;
    tieV1[tid] = V1;
    if (V2 - V1 < TAU) {  // near-tie: np-fp32 rescue decides
      const int pos = atomicAdd(rcnt, 1);
      rlist[pos] = blk * BM + tid;
      chosen[tid] = -1;
    } else {
      chosen[tid] = I1;
      out_idx[(size_t)(blk * BM + tid) * QLV + qlev] = (float)I1;
      atomicAdd(&counts[I1], 1.0f);
    }
  }
  __syncthreads();

  // ---- candidate collection for near-tie tokens (guarded by ws capacity) ----
  if (have_cand) {
#pragma unroll
    for (int tf = 0; tf < 4; ++tf)
#pragma unroll
      for (int r = 0; r < 4; ++r) {
        const int t = tf * 16 + (lane >> 4) * 4 + r;
        if (chosen[t] != -1) continue;
        const float thr = tieV1[t] + TAU;
#pragma unroll
        for (int h = 0; h < 2; ++h)
#pragma unroll
          for (int j = 0; j < 4; ++j) {
            const float dist = fmaf(-2.f, acc[h][j][tf][r], cnv[h][j]);
            if (dist < thr) {
              const int c = (h * 32 + w + 8 * j) * 16 + col;
              const int pos = atomicAdd(&ccnt[t], 1);
              if (pos < RCAP) cand[(size_t)(blk * BM + t) * RCAP + pos] = c;
            }
          }
      }
    __syncthreads();
    if (tid < 64 && chosen[tid] == -1) cand_cnt[blk * BM + tid] = ccnt[tid];
  }

  {  // residual update (fp32 chain, bit-equal to np's) — fast-path tokens only
    const int tb = tid >> 3, part = tid & 7;  // 8 threads per token
    const size_t tok = (size_t)(blk * BM + tb);
    const int idx = chosen[tb];
    float sq = 0.f;
    if (idx >= 0) {
      const float4* cp = (const float4*)(cb + (size_t)idx * DIM);
      const float4* rp = (const float4*)(rin + tok * DIM);
      const float4* xp = (const float4*)(x + tok * DIM);
      float4* op = (float4*)(resid + tok * DIM);
#pragma unroll 4
      for (int kk = 0; kk < 16; ++kk) {
        const int d4 = part + kk * 8;
        const float4 r = rp[d4], c4 = cp[d4];
        float4 rn;
        rn.x = r.x - c4.x; rn.y = r.y - c4.y; rn.z = r.z - c4.z; rn.w = r.w - c4.w;
        sq += rn.x * rn.x + rn.y * rn.y + rn.z * rn.z + rn.w * rn.w;
        if (LAST) {
          const float4 xv = xp[d4];
          float4 qv;
          qv.x = xv.x - rn.x; qv.y = xv.y - rn.y; qv.z = xv.z - rn.z; qv.w = xv.w - rn.w;
          op[d4] = qv;  // quantized = x - residual_new
        } else {
          op[d4] = rn;
        }
      }
    }
#pragma unroll
    for (int off = 32; off; off >>= 1) sq += __shfl_down(sq, off);
    if (lane == 0) atomicAdd(commit, sq);
  }
}

// ===================== old fp32 path (fallback if ws too small) =============
template <bool FIRST, bool LAST>
__global__ __launch_bounds__(512, 2) void level_kernel(
    const float* __restrict__ x, float* __restrict__ resid,
    const float* __restrict__ cb, const float* __restrict__ cnorm,
    float* __restrict__ out_idx, float* __restrict__ counts,
    float* __restrict__ commit, int* __restrict__ rcnt,
    int* __restrict__ rlist, int qlev) {
  __shared__ float Rs[DC][BM + 4];
  __shared__ float Cs[DC][KCODE + 4];
  __shared__ int chosen[BM];

  const int tid = threadIdx.x;
  const int lane = tid & 63;
  const int ty = tid >> 6;
  const int tx = lane;
  const int blk = blockIdx.x;
  const float* rin = FIRST ? x : resid;

  float acc[8][16];
#pragma unroll
  for (int j = 0; j < 8; ++j)
#pragma unroll
    for (int g = 0; g < 16; ++g) acc[j][g] = 0.f;

  float4 pc[4];
  float4 pr;
  {
#pragma unroll
    for (int u = 0; u < 4; ++u) {
      const int f4 = tid + u * 512;
      const int code = f4 >> 1, d4 = f4 & 1;
      pc[u] = *(const float4*)(cb + (size_t)code * DIM + d4 * 4);
    }
    if (tid < 128) {
      const int tok = tid >> 1, d4 = tid & 1;
      pr = *(const float4*)(rin + (size_t)(blk * BM + tok) * DIM + d4 * 4);
    }
  }

  for (int dc = 0; dc < NCH; ++dc) {
    __syncthreads();
#pragma unroll
    for (int u = 0; u < 4; ++u) {
      const int f4 = tid + u * 512;
      const int code = f4 >> 1, d4 = f4 & 1;
      Cs[d4 * 4 + 0][code] = pc[u].x;
      Cs[d4 * 4 + 1][code] = pc[u].y;
      Cs[d4 * 4 + 2][code] = pc[u].z;
      Cs[d4 * 4 + 3][code] = pc[u].w;
    }
    if (tid < 128) {
      const int tok = tid >> 1, d4 = tid & 1;
      Rs[d4 * 4 + 0][tok] = pr.x;
      Rs[d4 * 4 + 1][tok] = pr.y;
      Rs[d4 * 4 + 2][tok] = pr.z;
      Rs[d4 * 4 + 3][tok] = pr.w;
    }
    if (dc + 1 < NCH) {
      const int doff = (dc + 1) * DC;
#pragma unroll
      for (int u = 0; u < 4; ++u) {
        const int f4 = tid + u * 512;
        const int code = f4 >> 1, d4 = f4 & 1;
        pc[u] = *(const float4*)(cb + (size_t)code * DIM + doff + d4 * 4);
      }
      if (tid < 128) {
        const int tok = tid >> 1, d4 = tid & 1;
        pr = *(const float4*)(rin + (size_t)(blk * BM + tok) * DIM + doff + d4 * 4);
      }
    }
    __syncthreads();
#pragma unroll
    for (int d = 0; d < DC; ++d) {
      const float4 ra = *(const float4*)&Rs[d][ty * 8];
      const float4 rb = *(const float4*)&Rs[d][ty * 8 + 4];
#pragma unroll
      for (int q = 0; q < 4; ++q) {
        const float4 cv = *(const float4*)&Cs[d][q * 256 + tx * 4];
        const float c0 = cv.x, c1 = cv.y, c2 = cv.z, c3 = cv.w;
        acc[0][q * 4 + 0] = fmaf(ra.x, c0, acc[0][q * 4 + 0]);
        acc[0][q * 4 + 1] = fmaf(ra.x, c1, acc[0][q * 4 + 1]);
        acc[0][q * 4 + 2] = fmaf(ra.x, c2, acc[0][q * 4 + 2]);
        acc[0][q * 4 + 3] = fmaf(ra.x, c3, acc[0][q * 4 + 3]);
        acc[1][q * 4 + 0] = fmaf(ra.y, c0, acc[1][q * 4 + 0]);
        acc[1][q * 4 + 1] = fmaf(ra.y, c1, acc[1][q * 4 + 1]);
        acc[1][q * 4 + 2] = fmaf(ra.y, c2, acc[1][q * 4 + 2]);
        acc[1][q * 4 + 3] = fmaf(ra.y, c3, acc[1][q * 4 + 3]);
        acc[2][q * 4 + 0] = fmaf(ra.z, c0, acc[2][q * 4 + 0]);
        acc[2][q * 4 + 1] = fmaf(ra.z, c1, acc[2][q * 4 + 1]);
        acc[2][q * 4 + 2] = fmaf(ra.z, c2, acc[2][q * 4 + 2]);
        acc[2][q * 4 + 3] = fmaf(ra.z, c3, acc[2][q * 4 + 3]);
        acc[3][q * 4 + 0] = fmaf(ra.w, c0, acc[3][q * 4 + 0]);
        acc[3][q * 4 + 1] = fmaf(ra.w, c1, acc[3][q * 4 + 1]);
        acc[3][q * 4 + 2] = fmaf(ra.w, c2, acc[3][q * 4 + 2]);
        acc[3][q * 4 + 3] = fmaf(ra.w, c3, acc[3][q * 4 + 3]);
        acc[4][q * 4 + 0] = fmaf(rb.x, c0, acc[4][q * 4 + 0]);
        acc[4][q * 4 + 1] = fmaf(rb.x, c1, acc[4][q * 4 + 1]);
        acc[4][q * 4 + 2] = fmaf(rb.x, c2, acc[4][q * 4 + 2]);
        acc[4][q * 4 + 3] = fmaf(rb.x, c3, acc[4][q * 4 + 3]);
        acc[5][q * 4 + 0] = fmaf(rb.y, c0, acc[5][q * 4 + 0]);
        acc[5][q * 4 + 1] = fmaf(rb.y, c1, acc[5][q * 4 + 1]);
        acc[5][q * 4 + 2] = fmaf(rb.y, c2, acc[5][q * 4 + 2]);
        acc[5][q * 4 + 3] = fmaf(rb.y, c3, acc[5][q * 4 + 3]);
        acc[6][q * 4 + 0] = fmaf(rb.z, c0, acc[6][q * 4 + 0]);
        acc[6][q * 4 + 1] = fmaf(rb.z, c1, acc[6][q * 4 + 1]);
        acc[6][q * 4 + 2] = fmaf(rb.z, c2, acc[6][q * 4 + 2]);
        acc[6][q * 4 + 3] = fmaf(rb.z, c3, acc[6][q * 4 + 3]);
        acc[7][q * 4 + 0] = fmaf(rb.w, c0, acc[7][q * 4 + 0]);
        acc[7][q * 4 + 1] = fmaf(rb.w, c1, acc[7][q * 4 + 1]);
        acc[7][q * 4 + 2] = fmaf(rb.w, c2, acc[7][q * 4 + 2]);
        acc[7][q * 4 + 3] = fmaf(rb.w, c3, acc[7][q * 4 + 3]);
      }
    }
  }

  float v1[8], v2[8];
  int i1[8], i2[8];
#pragma unroll
  for (int j = 0; j < 8; ++j) { v1[j] = v2[j] = 3.4e38f; i1[j] = i2[j] = KCODE; }
#pragma unroll
  for (int g = 0; g < 16; ++g) {
    const int c = (g >> 2) * 256 + tx * 4 + (g & 3);
    const float cn = cnorm[c];
#pragma unroll
    for (int j = 0; j < 8; ++j) {
      const float dist = fmaf(-2.f, acc[j][g], cn);
      if (lt2(dist, c, v1[j], i1[j])) {
        v2[j] = v1[j]; i2[j] = i1[j]; v1[j] = dist; i1[j] = c;
      } else if (lt2(dist, c, v2[j], i2[j])) {
        v2[j] = dist; i2[j] = c;
      }
    }
  }
#pragma unroll
  for (int off = 1; off < 64; off <<= 1) {
#pragma unroll
    for (int j = 0; j < 8; ++j) {
      const float w1 = __shfl_xor(v1[j], off);
      const int j1 = __shfl_xor(i1[j], off);
      const float w2 = __shfl_xor(v2[j], off);
      const int j2 = __shfl_xor(i2[j], off);
      if (lt2(w1, j1, v1[j], i1[j])) {
        if (lt2(v1[j], i1[j], w2, j2)) { v2[j] = v1[j]; i2[j] = i1[j]; }
        else { v2[j] = w2; i2[j] = j2; }
        v1[j] = w1; i1[j] = j1;
      } else {
        if (lt2(w1, j1, v2[j], i2[j])) { v2[j] = w1; i2[j] = j1; }
      }
    }
  }
  if (lane < 8) {
    const int tb = ty * 8 + lane;
    const float V1 = v1[lane], V2 = v2[lane];
    const int I1 = i1[lane];
    if (V2 - V1 < TAU) {
      const int pos = atomicAdd(rcnt, 1);
      rlist[pos] = blk * BM + tb;
      chosen[tb] = -1;
    } else {
      chosen[tb] = I1;
      out_idx[(size_t)(blk * BM + tb) * QLV + qlev] = (float)I1;
      atomicAdd(&counts[I1], 1.0f);
    }
  }
  __syncthreads();
  {
    const int tb = tid >> 3, part = tid & 7;
    const size_t tok = (size_t)(blk * BM + tb);
    const int idx = chosen[tb];
    float sq = 0.f;
    if (idx >= 0) {
      const float4* cp = (const float4*)(cb + (size_t)idx * DIM);
      const float4* rp = (const float4*)(rin + tok * DIM);
      const float4* xp = (const float4*)(x + tok * DIM);
      float4* op = (float4*)(resid + tok * DIM);
#pragma unroll 4
      for (int kk = 0; kk < 16; ++kk) {
        const int d4 = part + kk * 8;
        const float4 r = rp[d4], c4 = cp[d4];
        float4 rn;
        rn.x = r.x - c4.x; rn.y = r.y - c4.y; rn.z = r.z - c4.z; rn.w = r.w - c4.w;
        sq += rn.x * rn.x + rn.y * rn.y + rn.z * rn.z + rn.w * rn.w;
        if (LAST) {
          const float4 xv = xp[d4];
          float4 qv;
          qv.x = xv.x - rn.x; qv.y = xv.y - rn.y; qv.z = xv.z - rn.z; qv.w = xv.w - rn.w;
          op[d4] = qv;
        } else {
          op[d4] = rn;
        }
      }
    }
#pragma unroll
    for (int off = 32; off; off >>= 1) sq += __shfl_down(sq, off);
    if (lane == 0) atomicAdd(commit, sq);
  }
}

// Near-tie finalization replicating numpy-fp32 semantics exactly (PROVEN r4).
// Candidate fast path: np-evaluate only the provably-sufficient candidate set.
template <bool LAST>
__global__ __launch_bounds__(256) void rescue_np(
    const float* __restrict__ x, const float* __restrict__ rin,
    float* __restrict__ resid, const float* __restrict__ cbq,
    const float* __restrict__ cnq, float* __restrict__ out_idx,
    float* __restrict__ counts, float* __restrict__ commit,
    const int* __restrict__ rcnt, const int* __restrict__ rlist,
    const int* __restrict__ cand_cnt, const int* __restrict__ cand,
    int have_cand, int qlev) {
  __shared__ float rsh[DIM];
  __shared__ __align__(16) float crows[RCAP][DIM];
  __shared__ float sA;
  __shared__ float wv[4];
  __shared__ int wi[4];
  __shared__ int bestk_s;
  const int tid = threadIdx.x;
  const int n = rcnt[0];
  for (int it = blockIdx.x; it < n; it += gridDim.x) {
    const int t = rlist[it];
    rsh[tid] = rin[(size_t)t * DIM + tid];
    rsh[256 + tid] = rin[(size_t)t * DIM + 256 + tid];
    __syncthreads();
    if (tid == 0) sA = np_sum512_sq(rsh);
    __syncthreads();
    const float A = sA;
    float bv = 3.4e38f;
    int bi = KCODE;
    const int m = have_cand ? cand_cnt[t] : (RCAP + 1);
    if (m <= RCAP) {
      // stage candidate rows into LDS (coalesced), then np_dist each
      for (int c = 0; c < m; ++c) {
        const int k = cand[(size_t)t * RCAP + c];
        crows[c][tid] = cbq[(size_t)k * DIM + tid];
        crows[c][256 + tid] = cbq[(size_t)k * DIM + 256 + tid];
      }
      __syncthreads();
      for (int c = tid; c < m; c += 256) {
        const int k = cand[(size_t)t * RCAP + c];
        const float d = np_dist(A, rsh, &crows[c][0], cnq[k]);
        if (d < bv || (d == bv && k < bi)) { bv = d; bi = k; }
      }
    } else {
      for (int kk = 0; kk < 4; ++kk) {
        const int k = tid * 4 + kk;  // ascending per thread -> first-occurrence ties
        const float d = np_dist(A, rsh, cbq + (size_t)k * DIM, cnq[k]);
        if (d < bv) { bv = d; bi = k; }
      }
    }
#pragma unroll
    for (int off = 32; off; off >>= 1) {
      const float ov = __shfl_down(bv, off);
      const int oi = __shfl_down(bi, off);
      if (ov < bv || (ov == bv && oi < bi)) { bv = ov; bi = oi; }
    }
    if ((tid & 63) == 0) { wv[tid >> 6] = bv; wi[tid >> 6] = bi; }
    __syncthreads();
    if (tid == 0) {
      float V = wv[0]; int I = wi[0];
#pragma unroll
      for (int w = 1; w < 4; ++w)
        if (wv[w] < V || (wv[w] == V && wi[w] < I)) { V = wv[w]; I = wi[w]; }
      bestk_s = I;
      out_idx[(size_t)t * QLV + qlev] = (float)I;
      atomicAdd(&counts[I], 1.0f);
    }
    __syncthreads();
    const float* crow = cbq + (size_t)bestk_s * DIM;
    float sq;
    {
      const int d0 = tid, d1 = tid + 256;
      const float rn0 = rsh[d0] - crow[d0];
      const float rn1 = rsh[d1] - crow[d1];
      sq = rn0 * rn0 + rn1 * rn1;
      if (LAST) {
        resid[(size_t)t * DIM + d0] = x[(size_t)t * DIM + d0] - rn0;
        resid[(size_t)t * DIM + d1] = x[(size_t)t * DIM + d1] - rn1;
      } else {
        resid[(size_t)t * DIM + d0] = rn0;
        resid[(size_t)t * DIM + d1] = rn1;
      }
    }
#pragma unroll
    for (int off = 32; off; off >>= 1) sq += __shfl_down(sq, off);
    if ((tid & 63) == 0) wv[tid >> 6] = sq;
    __syncthreads();
    if (tid == 0)
      atomicAdd(commit, wv[0] + wv[1] + wv[2] + wv[3]);
    __syncthreads();  // protect rsh/crows/wv before next list item
  }
}

__global__ __launch_bounds__(256) void finalize_scalars(const float* __restrict__ counts,
                                                        const float* __restrict__ commit,
                                                        float* __restrict__ out2) {
  const int tid = threadIdx.x;
  __shared__ float sh[4];
  __shared__ float perp_acc;
  if (tid == 0) perp_acc = 0.f;
  __syncthreads();
  for (int q = 0; q < QLV; ++q) {
    float h = 0.f;
    for (int k = tid; k < KCODE; k += 256) {
      const float p = counts[q * KCODE + k] * (1.0f / (float)NTOK);
      h += p * logf(p + 1e-10f);
    }
#pragma unroll
    for (int off = 32; off; off >>= 1) h += __shfl_down(h, off);
    if ((tid & 63) == 0) sh[tid >> 6] = h;
    __syncthreads();
    if (tid == 0) {
      const float H = sh[0] + sh[1] + sh[2] + sh[3];
      perp_acc += expf(-H);
    }
    __syncthreads();
  }
  if (tid == 0) {
    float closs = 0.f;
    for (int q = 0; q < QLV; ++q) closs += commit[q];
    out2[0] = closs * (0.25f / ((float)NTOK * (float)DIM));
    out2[1] = perp_acc * (1.0f / (float)QLV);
  }
}

extern "C" void kernel_launch(void* const* d_in, const int* in_sizes, int n_in,
                              void* d_out, int out_size, void* d_ws, size_t ws_size,
                              hipStream_t stream) {
  const float* x = (const float*)d_in[0];
  const float* cb = (const float*)d_in[1];
  float* out = (float*)d_out;
  float* ws = (float*)d_ws;

  float* resid = out;
  float* oidx = out + (size_t)NTOK * DIM;
  float* scal = oidx + (size_t)NTOK * QLV;
  float* counts = ws;
  float* commit = ws + QLV * KCODE;
  int* rcnt = (int*)(ws + QLV * KCODE + QLV);
  float* cnorm = ws + QLV * KCODE + 512;
  int* rlist = (int*)(ws + QLV * KCODE + 512 + QLV * KCODE);
  unsigned short* cbsplit = (unsigned short*)(ws + CBSPLIT_FLOAT_OFF);

  const size_t csplit_floats = (size_t)QLV * NCK * CHUNKB / 4;
  int* cand_cnt = (int*)(ws + CBSPLIT_FLOAT_OFF + csplit_floats);
  int* cand = cand_cnt + NTOK;
  const size_t need_mfma = ((size_t)CBSPLIT_FLOAT_OFF + csplit_floats) * 4;
  const size_t need_cand = need_mfma + (size_t)NTOK * (RCAP + 1) * 4;
  const bool use_mfma = ws_size >= need_mfma;
  const int have_cand = (use_mfma && ws_size >= need_cand) ? 1 : 0;

  hipLaunchKernelGGL(zero_ws, dim3(32), dim3(256), 0, stream, ws);
  hipLaunchKernelGGL(cnorm_np_kernel, dim3((QLV * KCODE) / 256), dim3(256), 0, stream,
                     cb, cnorm);
  if (use_mfma)
    hipLaunchKernelGGL(split_cb_kernel, dim3((QLV * KCODE * DIM / 4) / 256), dim3(256), 0,
                       stream, cb, cbsplit);

  for (int q = 0; q < QLV; ++q) {
    const float* cbq = cb + (size_t)q * KCODE * DIM;
    const float* cnq = cnorm + q * KCODE;
    float* ctq = counts + q * KCODE;
    float* cmq = commit + q;
    int* rcq = rcnt + q;
    const float* rin = (q == 0) ? x : resid;
    if (use_mfma) {
      const unsigned short* csq = cbsplit + (size_t)q * (NCK * CHUNKB / 2);
      if (q == 0)
        hipLaunchKernelGGL((level_mfma<true, false>), dim3(NTOK / BM), dim3(512), 0, stream,
                           x, resid, cbq, csq, cnq, oidx, ctq, cmq, rcq, rlist,
                           cand_cnt, cand, have_cand, q);
      else if (q == QLV - 1)
        hipLaunchKernelGGL((level_mfma<false, true>), dim3(NTOK / BM), dim3(512), 0, stream,
                           x, resid, cbq, csq, cnq, oidx, ctq, cmq, rcq, rlist,
                           cand_cnt, cand, have_cand, q);
      else
        hipLaunchKernelGGL((level_mfma<false, false>), dim3(NTOK / BM), dim3(512), 0, stream,
                           x, resid, cbq, csq, cnq, oidx, ctq, cmq, rcq, rlist,
                           cand_cnt, cand, have_cand, q);
    } else {
      if (q == 0)
        hipLaunchKernelGGL((level_kernel<true, false>), dim3(NTOK / BM), dim3(512), 0, stream,
                           x, resid, cbq, cnq, oidx, ctq, cmq, rcq, rlist, q);
      else if (q == QLV - 1)
        hipLaunchKernelGGL((level_kernel<false, true>), dim3(NTOK / BM), dim3(512), 0, stream,
                           x, resid, cbq, cnq, oidx, ctq, cmq, rcq, rlist, q);
      else
        hipLaunchKernelGGL((level_kernel<false, false>), dim3(NTOK / BM), dim3(512), 0, stream,
                           x, resid, cbq, cnq, oidx, ctq, cmq, rcq, rlist, q);
    }
    if (q == QLV - 1)
      hipLaunchKernelGGL((rescue_np<true>), dim3(256), dim3(256), 0, stream,
                         x, rin, resid, cbq, cnq, oidx, ctq, cmq, rcq, rlist,
                         cand_cnt, cand, have_cand, q);
    else
      hipLaunchKernelGGL((rescue_np<false>), dim3(256), dim3(256), 0, stream,
                         x, rin, resid, cbq, cnq, oidx, ctq, cmq, rcq, rlist,
                         cand_cnt, cand, have_cand, q);
  }
  hipLaunchKernelGGL(finalize_scalars, dim3(1), dim3(256), 0, stream, counts, commit, scal);
}

// Round 3
// 1057.038 us; speedup vs baseline: 2.5297x; 1.1030x over previous
//
#include <hip/hip_runtime.h>
#include <math.h>

#define NTOK 16384
#define DIM 512
#define QLV 8
#define KCODE 1024
#define BM 64
#define DC 8
#define NCH (DIM / DC)  // 64 d-chunks (old path)
#define TAU 1e-3f       // bf16x3 MFMA adds <=2.5e-4 abs error; TAU >= 2*eps

// ---- MFMA path constants ----
#define NCK 16          // 16 chunks of 32 d
#define CHUNKB 131072   // bytes per chunk in split-cb: 2 halves x (hi+lo) x 512 codes x 64 B
#define CBSPLIT_FLOAT_OFF 65536  // float offset of split-cb region inside ws (256 KB in)
#define RCAP 16         // per-token rescue candidate cap

typedef __attribute__((ext_vector_type(4))) float f32x4;
typedef __attribute__((ext_vector_type(8))) short bf16x8;

__global__ __launch_bounds__(256) void zero_ws(float* ws) {
  int i = blockIdx.x * 256 + threadIdx.x;
  for (int k = i; k < QLV * KCODE + 2 * QLV; k += gridDim.x * 256) ws[k] = 0.f;
}

// ---- numpy float32 replication helpers (PROVEN in round 4 — do not touch) --
__device__ __forceinline__ float np_blk128_sq(const float* __restrict__ x) {
#pragma clang fp contract(off)
  float L[16];
#pragma unroll
  for (int j = 0; j < 16; ++j) {
    const float a0 = x[j] * x[j];
    const float a1 = x[16 + j] * x[16 + j];
    const float a2 = x[32 + j] * x[32 + j];
    const float a3 = x[48 + j] * x[48 + j];
    const float a4 = x[64 + j] * x[64 + j];
    const float a5 = x[80 + j] * x[80 + j];
    const float a6 = x[96 + j] * x[96 + j];
    const float a7 = x[112 + j] * x[112 + j];
    L[j] = ((a0 + a1) + (a2 + a3)) + ((a4 + a5) + (a6 + a7));
  }
  float T3[8];
#pragma unroll
  for (int i = 0; i < 8; ++i) T3[i] = L[i] + L[i + 8];
  float T6[4];
#pragma unroll
  for (int j = 0; j < 4; ++j) T6[j] = T3[j] + T3[j + 4];
  return (T6[0] + T6[2]) + (T6[1] + T6[3]);
}

__device__ __forceinline__ float np_sum512_sq(const float* __restrict__ x) {
#pragma clang fp contract(off)
  const float p0 = np_blk128_sq(x);
  const float p1 = np_blk128_sq(x + 128);
  const float p2 = np_blk128_sq(x + 256);
  const float p3 = np_blk128_sq(x + 384);
  const float s01 = p0 + p1;
  const float s23 = p2 + p3;
  return s01 + s23;
}

__device__ __forceinline__ float np_dist(float A, const float* __restrict__ r,
                                         const float* __restrict__ c, float cn) {
#pragma clang fp contract(off)
  float b1 = 0.f;
#pragma unroll 8
  for (int d = 0; d < 384; ++d) b1 = __builtin_fmaf(r[d], c[d], b1);
  float b2 = 0.f;
#pragma unroll 8
  for (int d = 384; d < 512; ++d) b2 = __builtin_fmaf(r[d], c[d], b2);
  const float B = b1 + b2;
  const float t1 = 2.0f * B;
  const float t2 = A - t1;
  return t2 + cn;
}
// ---------------------------------------------------------------------------

__global__ __launch_bounds__(256) void cnorm_np_kernel(const float* __restrict__ cb,
                                                       float* __restrict__ cn) {
  const int row = blockIdx.x * 256 + threadIdx.x;  // [0, Q*K)
  cn[row] = np_sum512_sq(cb + (size_t)row * DIM);
}

// lexicographic (val, idx) less-than
__device__ __forceinline__ bool lt2(float a, int ia, float b, int ib) {
  return a < b || (a == b && ia < ib);
}

// ---- bf16 split helpers (RTNE) ----
__device__ __forceinline__ unsigned short bf16_rtne(float x) {
  unsigned u = __builtin_bit_cast(unsigned, x);
  u += 0x7FFFu + ((u >> 16) & 1u);
  return (unsigned short)(u >> 16);
}
__device__ __forceinline__ float bf16_tof(unsigned short h) {
  unsigned u = (unsigned)h << 16;
  return __builtin_bit_cast(float, u);
}
__device__ __forceinline__ void split2(float x, unsigned short& h, unsigned short& l) {
  h = bf16_rtne(x);
  l = bf16_rtne(x - bf16_tof(h));
}

__device__ __forceinline__ void gload16(const void* g, void* l) {
  __builtin_amdgcn_global_load_lds(
      (const __attribute__((address_space(1))) unsigned int*)g,
      (__attribute__((address_space(3))) unsigned int*)l, 16, 0, 0);
}

// One-time: split fp32 codebooks into pre-swizzled bf16 hi/lo tiles in ws.
// Layout per (q,chunk): [half(2)][hi 32KB | lo 32KB][512 codes][64 B], with
// in-code slot swizzle slot = kb ^ ((cl>>1)&3) so a linear LDS image is
// bank-conflict-free for frag ds_read_b128.
__global__ __launch_bounds__(256) void split_cb_kernel(const float* __restrict__ cb,
                                                       unsigned short* __restrict__ dst) {
  const int f = blockIdx.x * 256 + threadIdx.x;  // float4 index, 2^20 total
  const int d4 = f & 127;
  const int c = (f >> 7) & 1023;
  const int q = f >> 17;
  const float4 v = *(const float4*)(cb + (size_t)f * 4);
  const int d0 = d4 * 4;
  const int dc = d0 >> 5;
  const int e = d0 & 31;
  const int kb = e >> 3;
  const int e7 = e & 7;  // 0 or 4
  const int half = c >> 9, cl = c & 511;
  const int slot = kb ^ ((cl >> 1) & 3);
  const size_t base = (size_t)(q * NCK + dc) * CHUNKB + (size_t)half * 65536;
  const size_t off = base + (size_t)cl * 64 + (size_t)slot * 16 + (size_t)e7 * 2;
  unsigned short h0, l0, h1, l1, h2, l2, h3, l3;
  split2(v.x, h0, l0);
  split2(v.y, h1, l1);
  split2(v.z, h2, l2);
  split2(v.w, h3, l3);
  uint2 hv, lv;
  hv.x = (unsigned)h0 | ((unsigned)h1 << 16);
  hv.y = (unsigned)h2 | ((unsigned)h3 << 16);
  lv.x = (unsigned)l0 | ((unsigned)l1 << 16);
  lv.y = (unsigned)l2 | ((unsigned)l3 << 16);
  char* db = (char*)dst;
  *(uint2*)(db + off) = hv;            // hi plane
  *(uint2*)(db + off + 32768) = lv;    // lo plane
}

// ===================== MFMA level kernel (wave-private B, barrier-free) =====
// Block: 64 tokens x 1024 codes, 512 threads (8 waves).
// Wave w owns code-frags cf = w + 8*j (j=0..7); it loads ONLY its own B bytes
// into a private LDS ring (8 slots x 2KB), so B needs no barriers: per pair
// {vmcnt(N) -> 2x ds_read_b128 -> 12 MFMA}, prefetch distance 6 pairs.
// Shared A tile: 1 raw s_barrier + lgkmcnt(0) per 32-d chunk (no vmcnt drain).
#define VMW(N) asm volatile("s_waitcnt vmcnt(" #N ")" ::: "memory")

template <bool FIRST, bool LAST>
__global__ __launch_bounds__(512, 2) void level_mfma(
    const float* __restrict__ x, float* __restrict__ resid,
    const float* __restrict__ cb, const unsigned short* __restrict__ cbsplit,
    const float* __restrict__ cnorm, float* __restrict__ out_idx,
    float* __restrict__ counts, float* __restrict__ commit, int* __restrict__ rcnt,
    int* __restrict__ rlist, int* __restrict__ cand_cnt, int* __restrict__ cand,
    int have_cand, int qlev) {
  __shared__ __align__(16) unsigned char Bring[8][8][2048];  // [wave][slot][hi1K|lo1K]
  __shared__ __align__(16) unsigned char As[16384];          // [buf][hl][64][64B]
  __shared__ __align__(16) float foldb[64][8][4];
  __shared__ int chosen[64];
  __shared__ float tieV1[64];
  __shared__ int ccnt[64];

  const int tid = threadIdx.x;
  const int lane = tid & 63;
  const int w = tid >> 6;
  const int col = lane & 15;
  const int kb = lane >> 4;
  const int blk = blockIdx.x;
  const float* rin = FIRST ? x : resid;
  const char* csp = (const char*)cbsplit;
  unsigned char* bringw = &Bring[w][0][0];
  const int bcol = col * 64 + ((kb ^ ((col >> 1) & 3)) << 4);

  // per-frag B source offsets (within a chunk region)
  size_t srcoff[8];
#pragma unroll
  for (int jp = 0; jp < 8; ++jp) {
    const int cf = w + 8 * jp;
    srcoff[jp] = (size_t)(cf >> 5) * 65536 + (size_t)(cf & 31) * 1024 + (size_t)lane * 16;
  }
  // A read offsets (per tf)
  int rdA[4];
#pragma unroll
  for (int tf = 0; tf < 4; ++tf) {
    const int row = tf * 16 + col;
    rdA[tf] = row * 64 + ((kb ^ ((row >> 1) & 3)) << 4);
  }

  // A-staging geometry: thread -> (row, 4 d's)
  const int arow = tid >> 3;
  const int ae0 = (tid & 7) * 4;
  const int akb = ae0 >> 3;
  const int aslot = akb ^ ((arow >> 1) & 3);
  const size_t abyte = (size_t)arow * 64 + (size_t)aslot * 16 + (size_t)(ae0 & 7) * 2;
  const float* aglob = rin + (size_t)(blk * BM + arow) * DIM + ae0;

  f32x4 acc[8][4];
#pragma unroll
  for (int j = 0; j < 8; ++j)
#pragma unroll
    for (int tf = 0; tf < 4; ++tf) acc[j][tf] = (f32x4){0.f, 0.f, 0.f, 0.f};

#define LM_ISSUE(PDC, JP)                                          \
  {                                                                \
    const char* s_ = csp + (size_t)(PDC)*CHUNKB + srcoff[JP];      \
    unsigned char* d_ = bringw + (JP)*2048;                        \
    gload16(s_, d_);                                               \
    gload16(s_ + 32768, d_ + 1024);                                \
  }

#define LM_COMPUTE(JJ)                                                                   \
  {                                                                                      \
    const unsigned char* sb_ = bringw + (JJ)*2048 + bcol;                                \
    const bf16x8 bh_ = *(const bf16x8*)sb_;                                              \
    const bf16x8 bl_ = *(const bf16x8*)(sb_ + 1024);                                     \
    __builtin_amdgcn_s_setprio(1);                                                       \
    _Pragma("unroll") for (int tf = 0; tf < 4; ++tf) {                                   \
      acc[JJ][tf] = __builtin_amdgcn_mfma_f32_16x16x32_bf16(ah[tf], bh_, acc[JJ][tf], 0, 0, 0); \
      acc[JJ][tf] = __builtin_amdgcn_mfma_f32_16x16x32_bf16(al[tf], bh_, acc[JJ][tf], 0, 0, 0); \
      acc[JJ][tf] = __builtin_amdgcn_mfma_f32_16x16x32_bf16(ah[tf], bl_, acc[JJ][tf], 0, 0, 0); \
    }                                                                                    \
    __builtin_amdgcn_s_setprio(0);                                                       \
  }

#define LM_ASPLIT(BUF)                                             \
  {                                                                \
    unsigned short h0, l0, h1, l1, h2, l2, h3, l3;                 \
    split2(pAn.x, h0, l0);                                         \
    split2(pAn.y, h1, l1);                                         \
    split2(pAn.z, h2, l2);                                         \
    split2(pAn.w, h3, l3);                                         \
    uint2 hv, lv;                                                  \
    hv.x = (unsigned)h0 | ((unsigned)h1 << 16);                    \
    hv.y = (unsigned)h2 | ((unsigned)h3 << 16);                    \
    lv.x = (unsigned)l0 | ((unsigned)l1 << 16);                    \
    lv.y = (unsigned)l2 | ((unsigned)l3 << 16);                    \
    const size_t ab0_ = (size_t)(BUF)*8192 + abyte;                \
    *(uint2*)&As[ab0_] = hv;                                       \
    *(uint2*)&As[4096 + ab0_] = lv;                                \
  }

  // ---- prologue: A(0) -> As[0]; issue pairs 0..5 of chunk 0 ----
  {
    const float4 pAn = *(const float4*)aglob;  // compiler waits vmcnt for this only
    LM_ISSUE(0, 0); LM_ISSUE(0, 1); LM_ISSUE(0, 2);
    LM_ISSUE(0, 3); LM_ISSUE(0, 4); LM_ISSUE(0, 5);
    LM_ASPLIT(0);
  }
  asm volatile("s_waitcnt lgkmcnt(0)" ::: "memory");
  __builtin_amdgcn_s_barrier();

  // ---- generic chunks 0..14 (A prefetch for dc+1) ----
  for (int dc = 0; dc < NCK - 1; ++dc) {
    const int abuf = dc & 1;
    bf16x8 ah[4], al[4];
#pragma unroll
    for (int tf = 0; tf < 4; ++tf) {
      const size_t ab = (size_t)abuf * 8192 + (size_t)rdA[tf];
      ah[tf] = *(const bf16x8*)&As[ab];
      al[tf] = *(const bf16x8*)&As[ab + 4096];
    }
    float4 pAn;
    VMW(10); LM_ISSUE(dc, 6);
    pAn = *(const float4*)(aglob + (dc + 1) * 32);
    LM_COMPUTE(0);
    VMW(11); LM_ISSUE(dc, 7);     LM_COMPUTE(1);
    VMW(11); LM_ISSUE(dc + 1, 0); LM_COMPUTE(2);
    VMW(11); LM_ISSUE(dc + 1, 1); LM_COMPUTE(3);
    VMW(11); LM_ISSUE(dc + 1, 2); LM_COMPUTE(4);
    VMW(11); LM_ISSUE(dc + 1, 3); LM_COMPUTE(5);
    LM_ASPLIT(abuf ^ 1);
    VMW(11); LM_ISSUE(dc + 1, 4); LM_COMPUTE(6);
    VMW(10); LM_ISSUE(dc + 1, 5); LM_COMPUTE(7);
    asm volatile("s_waitcnt lgkmcnt(0)" ::: "memory");
    __builtin_amdgcn_s_barrier();
  }

  // ---- final chunk 15 (tail waits, no A prefetch) ----
  {
    bf16x8 ah[4], al[4];
#pragma unroll
    for (int tf = 0; tf < 4; ++tf) {
      const size_t ab = (size_t)8192 + (size_t)rdA[tf];  // buf 1 (15&1)
      ah[tf] = *(const bf16x8*)&As[ab];
      al[tf] = *(const bf16x8*)&As[ab + 4096];
    }
    VMW(10); LM_ISSUE(15, 6); LM_COMPUTE(0);
    VMW(10); LM_ISSUE(15, 7); LM_COMPUTE(1);
    VMW(10); LM_COMPUTE(2);
    VMW(8);  LM_COMPUTE(3);
    VMW(6);  LM_COMPUTE(4);
    VMW(4);  LM_COMPUTE(5);
    VMW(2);  LM_COMPUTE(6);
    VMW(0);  LM_COMPUTE(7);
  }
  __syncthreads();

  // ---- epilogue: fold top-2 per token over this wave's 128 codes ----
  float cnv[8];
#pragma unroll
  for (int j = 0; j < 8; ++j) cnv[j] = cnorm[(w + 8 * j) * 16 + col];

#pragma unroll
  for (int tf = 0; tf < 4; ++tf) {
#pragma unroll
    for (int r = 0; r < 4; ++r) {
      float b1 = 3.4e38f, b2 = 3.4e38f;
      int x1 = KCODE, x2 = KCODE;
#pragma unroll
      for (int j = 0; j < 8; ++j) {
        const int c = (w + 8 * j) * 16 + col;
        const float dist = fmaf(-2.f, acc[j][tf][r], cnv[j]);
        if (lt2(dist, c, b1, x1)) {
          b2 = b1; x2 = x1; b1 = dist; x1 = c;
        } else if (lt2(dist, c, b2, x2)) {
          b2 = dist; x2 = c;
        }
      }
      // butterfly across the 16 lanes of this col-group
#pragma unroll
      for (int off = 1; off < 16; off <<= 1) {
        const float w1 = __shfl_xor(b1, off);
        const int j1 = __shfl_xor(x1, off);
        const float w2 = __shfl_xor(b2, off);
        const int j2 = __shfl_xor(x2, off);
        if (lt2(w1, j1, b1, x1)) {
          if (lt2(b1, x1, w2, j2)) { b2 = b1; x2 = x1; }
          else { b2 = w2; x2 = j2; }
          b1 = w1; x1 = j1;
        } else if (lt2(w1, j1, b2, x2)) {
          b2 = w1; x2 = j1;
        }
      }
      if (col == 0) {
        const int t = tf * 16 + (lane >> 4) * 4 + r;
        float4 fv;
        fv.x = b1; fv.y = __int_as_float(x1); fv.z = b2; fv.w = __int_as_float(x2);
        *(float4*)&foldb[t][w][0] = fv;
      }
    }
  }
  __syncthreads();

  // ---- merge 8 wave-results per token; gap test; decide/rescue ----
  if (tid < 64) {
    float V1 = 3.4e38f, V2 = 3.4e38f;
    int I1 = KCODE, I2 = KCODE;
#pragma unroll
    for (int ww = 0; ww < 8; ++ww) {
      const float4 e = *(const float4*)&foldb[tid][ww][0];
      const float a1 = e.x, a2 = e.z;
      const int a1i = __float_as_int(e.y), a2i = __float_as_int(e.w);
      if (lt2(a1, a1i, V1, I1)) {
        if (lt2(V1, I1, a2, a2i)) { V2 = V1; I2 = I1; }
        else { V2 = a2; I2 = a2i; }
        V1 = a1; I1 = a1i;
      } else if (lt2(a1, a1i, V2, I2)) {
        V2 = a1; I2 = a1i;
      }
    }
    ccnt[tid] = 0;
    tieV1[tid] = V1;
    if (V2 - V1 < TAU) {  // near-tie: np-fp32 rescue decides
      const int pos = atomicAdd(rcnt, 1);
      rlist[pos] = blk * BM + tid;
      chosen[tid] = -1;
    } else {
      chosen[tid] = I1;
      out_idx[(size_t)(blk * BM + tid) * QLV + qlev] = (float)I1;
      atomicAdd(&counts[I1], 1.0f);
    }
  }
  __syncthreads();

  // ---- candidate collection for near-tie tokens (guarded by ws capacity) ----
  if (have_cand) {
#pragma unroll
    for (int tf = 0; tf < 4; ++tf)
#pragma unroll
      for (int r = 0; r < 4; ++r) {
        const int t = tf * 16 + (lane >> 4) * 4 + r;
        if (chosen[t] != -1) continue;
        const float thr = tieV1[t] + TAU;
#pragma unroll
        for (int j = 0; j < 8; ++j) {
          const float dist = fmaf(-2.f, acc[j][tf][r], cnv[j]);
          if (dist < thr) {
            const int c = (w + 8 * j) * 16 + col;
            const int pos = atomicAdd(&ccnt[t], 1);
            if (pos < RCAP) cand[(size_t)(blk * BM + t) * RCAP + pos] = c;
          }
        }
      }
    __syncthreads();
    if (tid < 64 && chosen[tid] == -1) cand_cnt[blk * BM + tid] = ccnt[tid];
  }

  {  // residual update (fp32 chain, bit-equal to np's) — fast-path tokens only
    const int tb = tid >> 3, part = tid & 7;  // 8 threads per token
    const size_t tok = (size_t)(blk * BM + tb);
    const int idx = chosen[tb];
    float sq = 0.f;
    if (idx >= 0) {
      const float4* cp = (const float4*)(cb + (size_t)idx * DIM);
      const float4* rp = (const float4*)(rin + tok * DIM);
      const float4* xp = (const float4*)(x + tok * DIM);
      float4* op = (float4*)(resid + tok * DIM);
#pragma unroll 4
      for (int kk = 0; kk < 16; ++kk) {
        const int d4 = part + kk * 8;
        const float4 r = rp[d4], c4 = cp[d4];
        float4 rn;
        rn.x = r.x - c4.x; rn.y = r.y - c4.y; rn.z = r.z - c4.z; rn.w = r.w - c4.w;
        sq += rn.x * rn.x + rn.y * rn.y + rn.z * rn.z + rn.w * rn.w;
        if (LAST) {
          const float4 xv = xp[d4];
          float4 qv;
          qv.x = xv.x - rn.x; qv.y = xv.y - rn.y; qv.z = xv.z - rn.z; qv.w = xv.w - rn.w;
          op[d4] = qv;  // quantized = x - residual_new
        } else {
          op[d4] = rn;
        }
      }
    }
#pragma unroll
    for (int off = 32; off; off >>= 1) sq += __shfl_down(sq, off);
    if (lane == 0) atomicAdd(commit, sq);
  }
}
#undef LM_ISSUE
#undef LM_COMPUTE
#undef LM_ASPLIT

// ===================== old fp32 path (fallback if ws too small) =============
template <bool FIRST, bool LAST>
__global__ __launch_bounds__(512, 2) void level_kernel(
    const float* __restrict__ x, float* __restrict__ resid,
    const float* __restrict__ cb, const float* __restrict__ cnorm,
    float* __restrict__ out_idx, float* __restrict__ counts,
    float* __restrict__ commit, int* __restrict__ rcnt,
    int* __restrict__ rlist, int qlev) {
  __shared__ float Rs[DC][BM + 4];
  __shared__ float Cs[DC][KCODE + 4];
  __shared__ int chosen[BM];

  const int tid = threadIdx.x;
  const int lane = tid & 63;
  const int ty = tid >> 6;
  const int tx = lane;
  const int blk = blockIdx.x;
  const float* rin = FIRST ? x : resid;

  float acc[8][16];
#pragma unroll
  for (int j = 0; j < 8; ++j)
#pragma unroll
    for (int g = 0; g < 16; ++g) acc[j][g] = 0.f;

  float4 pc[4];
  float4 pr;
  {
#pragma unroll
    for (int u = 0; u < 4; ++u) {
      const int f4 = tid + u * 512;
      const int code = f4 >> 1, d4 = f4 & 1;
      pc[u] = *(const float4*)(cb + (size_t)code * DIM + d4 * 4);
    }
    if (tid < 128) {
      const int tok = tid >> 1, d4 = tid & 1;
      pr = *(const float4*)(rin + (size_t)(blk * BM + tok) * DIM + d4 * 4);
    }
  }

  for (int dc = 0; dc < NCH; ++dc) {
    __syncthreads();
#pragma unroll
    for (int u = 0; u < 4; ++u) {
      const int f4 = tid + u * 512;
      const int code = f4 >> 1, d4 = f4 & 1;
      Cs[d4 * 4 + 0][code] = pc[u].x;
      Cs[d4 * 4 + 1][code] = pc[u].y;
      Cs[d4 * 4 + 2][code] = pc[u].z;
      Cs[d4 * 4 + 3][code] = pc[u].w;
    }
    if (tid < 128) {
      const int tok = tid >> 1, d4 = tid & 1;
      Rs[d4 * 4 + 0][tok] = pr.x;
      Rs[d4 * 4 + 1][tok] = pr.y;
      Rs[d4 * 4 + 2][tok] = pr.z;
      Rs[d4 * 4 + 3][tok] = pr.w;
    }
    if (dc + 1 < NCH) {
      const int doff = (dc + 1) * DC;
#pragma unroll
      for (int u = 0; u < 4; ++u) {
        const int f4 = tid + u * 512;
        const int code = f4 >> 1, d4 = f4 & 1;
        pc[u] = *(const float4*)(cb + (size_t)code * DIM + doff + d4 * 4);
      }
      if (tid < 128) {
        const int tok = tid >> 1, d4 = tid & 1;
        pr = *(const float4*)(rin + (size_t)(blk * BM + tok) * DIM + doff + d4 * 4);
      }
    }
    __syncthreads();
#pragma unroll
    for (int d = 0; d < DC; ++d) {
      const float4 ra = *(const float4*)&Rs[d][ty * 8];
      const float4 rb = *(const float4*)&Rs[d][ty * 8 + 4];
#pragma unroll
      for (int q = 0; q < 4; ++q) {
        const float4 cv = *(const float4*)&Cs[d][q * 256 + tx * 4];
        const float c0 = cv.x, c1 = cv.y, c2 = cv.z, c3 = cv.w;
        acc[0][q * 4 + 0] = fmaf(ra.x, c0, acc[0][q * 4 + 0]);
        acc[0][q * 4 + 1] = fmaf(ra.x, c1, acc[0][q * 4 + 1]);
        acc[0][q * 4 + 2] = fmaf(ra.x, c2, acc[0][q * 4 + 2]);
        acc[0][q * 4 + 3] = fmaf(ra.x, c3, acc[0][q * 4 + 3]);
        acc[1][q * 4 + 0] = fmaf(ra.y, c0, acc[1][q * 4 + 0]);
        acc[1][q * 4 + 1] = fmaf(ra.y, c1, acc[1][q * 4 + 1]);
        acc[1][q * 4 + 2] = fmaf(ra.y, c2, acc[1][q * 4 + 2]);
        acc[1][q * 4 + 3] = fmaf(ra.y, c3, acc[1][q * 4 + 3]);
        acc[2][q * 4 + 0] = fmaf(ra.z, c0, acc[2][q * 4 + 0]);
        acc[2][q * 4 + 1] = fmaf(ra.z, c1, acc[2][q * 4 + 1]);
        acc[2][q * 4 + 2] = fmaf(ra.z, c2, acc[2][q * 4 + 2]);
        acc[2][q * 4 + 3] = fmaf(ra.z, c3, acc[2][q * 4 + 3]);
        acc[3][q * 4 + 0] = fmaf(ra.w, c0, acc[3][q * 4 + 0]);
        acc[3][q * 4 + 1] = fmaf(ra.w, c1, acc[3][q * 4 + 1]);
        acc[3][q * 4 + 2] = fmaf(ra.w, c2, acc[3][q * 4 + 2]);
        acc[3][q * 4 + 3] = fmaf(ra.w, c3, acc[3][q * 4 + 3]);
        acc[4][q * 4 + 0] = fmaf(rb.x, c0, acc[4][q * 4 + 0]);
        acc[4][q * 4 + 1] = fmaf(rb.x, c1, acc[4][q * 4 + 1]);
        acc[4][q * 4 + 2] = fmaf(rb.x, c2, acc[4][q * 4 + 2]);
        acc[4][q * 4 + 3] = fmaf(rb.x, c3, acc[4][q * 4 + 3]);
        acc[5][q * 4 + 0] = fmaf(rb.y, c0, acc[5][q * 4 + 0]);
        acc[5][q * 4 + 1] = fmaf(rb.y, c1, acc[5][q * 4 + 1]);
        acc[5][q * 4 + 2] = fmaf(rb.y, c2, acc[5][q * 4 + 2]);
        acc[5][q * 4 + 3] = fmaf(rb.y, c3, acc[5][q * 4 + 3]);
        acc[6][q * 4 + 0] = fmaf(rb.z, c0, acc[6][q * 4 + 0]);
        acc[6][q * 4 + 1] = fmaf(rb.z, c1, acc[6][q * 4 + 1]);
        acc[6][q * 4 + 2] = fmaf(rb.z, c2, acc[6][q * 4 + 2]);
        acc[6][q * 4 + 3] = fmaf(rb.z, c3, acc[6][q * 4 + 3]);
        acc[7][q * 4 + 0] = fmaf(rb.w, c0, acc[7][q * 4 + 0]);
        acc[7][q * 4 + 1] = fmaf(rb.w, c1, acc[7][q * 4 + 1]);
        acc[7][q * 4 + 2] = fmaf(rb.w, c2, acc[7][q * 4 + 2]);
        acc[7][q * 4 + 3] = fmaf(rb.w, c3, acc[7][q * 4 + 3]);
      }
    }
  }

  float v1[8], v2[8];
  int i1[8], i2[8];
#pragma unroll
  for (int j = 0; j < 8; ++j) { v1[j] = v2[j] = 3.4e38f; i1[j] = i2[j] = KCODE; }
#pragma unroll
  for (int g = 0; g < 16; ++g) {
    const int c = (g >> 2) * 256 + tx * 4 + (g & 3);
    const float cn = cnorm[c];
#pragma unroll
    for (int j = 0; j < 8; ++j) {
      const float dist = fmaf(-2.f, acc[j][g], cn);
      if (lt2(dist, c, v1[j], i1[j])) {
        v2[j] = v1[j]; i2[j] = i1[j]; v1[j] = dist; i1[j] = c;
      } else if (lt2(dist, c, v2[j], i2[j])) {
        v2[j] = dist; i2[j] = c;
      }
    }
  }
#pragma unroll
  for (int off = 1; off < 64; off <<= 1) {
#pragma unroll
    for (int j = 0; j < 8; ++j) {
      const float w1 = __shfl_xor(v1[j], off);
      const int j1 = __shfl_xor(i1[j], off);
      const float w2 = __shfl_xor(v2[j], off);
      const int j2 = __shfl_xor(i2[j], off);
      if (lt2(w1, j1, v1[j], i1[j])) {
        if (lt2(v1[j], i1[j], w2, j2)) { v2[j] = v1[j]; i2[j] = i1[j]; }
        else { v2[j] = w2; i2[j] = j2; }
        v1[j] = w1; i1[j] = j1;
      } else {
        if (lt2(w1, j1, v2[j], i2[j])) { v2[j] = w1; i2[j] = j1; }
      }
    }
  }
  if (lane < 8) {
    const int tb = ty * 8 + lane;
    const float V1 = v1[lane], V2 = v2[lane];
    const int I1 = i1[lane];
    if (V2 - V1 < TAU) {
      const int pos = atomicAdd(rcnt, 1);
      rlist[pos] = blk * BM + tb;
      chosen[tb] = -1;
    } else {
      chosen[tb] = I1;
      out_idx[(size_t)(blk * BM + tb) * QLV + qlev] = (float)I1;
      atomicAdd(&counts[I1], 1.0f);
    }
  }
  __syncthreads();
  {
    const int tb = tid >> 3, part = tid & 7;
    const size_t tok = (size_t)(blk * BM + tb);
    const int idx = chosen[tb];
    float sq = 0.f;
    if (idx >= 0) {
      const float4* cp = (const float4*)(cb + (size_t)idx * DIM);
      const float4* rp = (const float4*)(rin + tok * DIM);
      const float4* xp = (const float4*)(x + tok * DIM);
      float4* op = (float4*)(resid + tok * DIM);
#pragma unroll 4
      for (int kk = 0; kk < 16; ++kk) {
        const int d4 = part + kk * 8;
        const float4 r = rp[d4], c4 = cp[d4];
        float4 rn;
        rn.x = r.x - c4.x; rn.y = r.y - c4.y; rn.z = r.z - c4.z; rn.w = r.w - c4.w;
        sq += rn.x * rn.x + rn.y * rn.y + rn.z * rn.z + rn.w * rn.w;
        if (LAST) {
          const float4 xv = xp[d4];
          float4 qv;
          qv.x = xv.x - rn.x; qv.y = xv.y - rn.y; qv.z = xv.z - rn.z; qv.w = xv.w - rn.w;
          op[d4] = qv;
        } else {
          op[d4] = rn;
        }
      }
    }
#pragma unroll
    for (int off = 32; off; off >>= 1) sq += __shfl_down(sq, off);
    if (lane == 0) atomicAdd(commit, sq);
  }
}

// Near-tie finalization replicating numpy-fp32 semantics exactly (PROVEN r4).
// Candidate fast path: np-evaluate only the provably-sufficient candidate set.
template <bool LAST>
__global__ __launch_bounds__(256) void rescue_np(
    const float* __restrict__ x, const float* __restrict__ rin,
    float* __restrict__ resid, const float* __restrict__ cbq,
    const float* __restrict__ cnq, float* __restrict__ out_idx,
    float* __restrict__ counts, float* __restrict__ commit,
    const int* __restrict__ rcnt, const int* __restrict__ rlist,
    const int* __restrict__ cand_cnt, const int* __restrict__ cand,
    int have_cand, int qlev) {
  __shared__ float rsh[DIM];
  __shared__ __align__(16) float crows[RCAP][DIM];
  __shared__ float sA;
  __shared__ float wv[4];
  __shared__ int wi[4];
  __shared__ int bestk_s;
  const int tid = threadIdx.x;
  const int n = rcnt[0];
  for (int it = blockIdx.x; it < n; it += gridDim.x) {
    const int t = rlist[it];
    rsh[tid] = rin[(size_t)t * DIM + tid];
    rsh[256 + tid] = rin[(size_t)t * DIM + 256 + tid];
    __syncthreads();
    if (tid == 0) sA = np_sum512_sq(rsh);
    __syncthreads();
    const float A = sA;
    float bv = 3.4e38f;
    int bi = KCODE;
    const int m = have_cand ? cand_cnt[t] : (RCAP + 1);
    if (m <= RCAP) {
      // stage candidate rows into LDS (coalesced), then np_dist each
      for (int c = 0; c < m; ++c) {
        const int k = cand[(size_t)t * RCAP + c];
        crows[c][tid] = cbq[(size_t)k * DIM + tid];
        crows[c][256 + tid] = cbq[(size_t)k * DIM + 256 + tid];
      }
      __syncthreads();
      for (int c = tid; c < m; c += 256) {
        const int k = cand[(size_t)t * RCAP + c];
        const float d = np_dist(A, rsh, &crows[c][0], cnq[k]);
        if (d < bv || (d == bv && k < bi)) { bv = d; bi = k; }
      }
    } else {
      for (int kk = 0; kk < 4; ++kk) {
        const int k = tid * 4 + kk;  // ascending per thread -> first-occurrence ties
        const float d = np_dist(A, rsh, cbq + (size_t)k * DIM, cnq[k]);
        if (d < bv) { bv = d; bi = k; }
      }
    }
#pragma unroll
    for (int off = 32; off; off >>= 1) {
      const float ov = __shfl_down(bv, off);
      const int oi = __shfl_down(bi, off);
      if (ov < bv || (ov == bv && oi < bi)) { bv = ov; bi = oi; }
    }
    if ((tid & 63) == 0) { wv[tid >> 6] = bv; wi[tid >> 6] = bi; }
    __syncthreads();
    if (tid == 0) {
      float V = wv[0]; int I = wi[0];
#pragma unroll
      for (int w = 1; w < 4; ++w)
        if (wv[w] < V || (wv[w] == V && wi[w] < I)) { V = wv[w]; I = wi[w]; }
      bestk_s = I;
      out_idx[(size_t)t * QLV + qlev] = (float)I;
      atomicAdd(&counts[I], 1.0f);
    }
    __syncthreads();
    const float* crow = cbq + (size_t)bestk_s * DIM;
    float sq;
    {
      const int d0 = tid, d1 = tid + 256;
      const float rn0 = rsh[d0] - crow[d0];
      const float rn1 = rsh[d1] - crow[d1];
      sq = rn0 * rn0 + rn1 * rn1;
      if (LAST) {
        resid[(size_t)t * DIM + d0] = x[(size_t)t * DIM + d0] - rn0;
        resid[(size_t)t * DIM + d1] = x[(size_t)t * DIM + d1] - rn1;
      } else {
        resid[(size_t)t * DIM + d0] = rn0;
        resid[(size_t)t * DIM + d1] = rn1;
      }
    }
#pragma unroll
    for (int off = 32; off; off >>= 1) sq += __shfl_down(sq, off);
    if ((tid & 63) == 0) wv[tid >> 6] = sq;
    __syncthreads();
    if (tid == 0)
      atomicAdd(commit, wv[0] + wv[1] + wv[2] + wv[3]);
    __syncthreads();  // protect rsh/crows/wv before next list item
  }
}

__global__ __launch_bounds__(256) void finalize_scalars(const float* __restrict__ counts,
                                                        const float* __restrict__ commit,
                                                        float* __restrict__ out2) {
  const int tid = threadIdx.x;
  __shared__ float sh[4];
  __shared__ float perp_acc;
  if (tid == 0) perp_acc = 0.f;
  __syncthreads();
  for (int q = 0; q < QLV; ++q) {
    float h = 0.f;
    for (int k = tid; k < KCODE; k += 256) {
      const float p = counts[q * KCODE + k] * (1.0f / (float)NTOK);
      h += p * logf(p + 1e-10f);
    }
#pragma unroll
    for (int off = 32; off; off >>= 1) h += __shfl_down(h, off);
    if ((tid & 63) == 0) sh[tid >> 6] = h;
    __syncthreads();
    if (tid == 0) {
      const float H = sh[0] + sh[1] + sh[2] + sh[3];
      perp_acc += expf(-H);
    }
    __syncthreads();
  }
  if (tid == 0) {
    float closs = 0.f;
    for (int q = 0; q < QLV; ++q) closs += commit[q];
    out2[0] = closs * (0.25f / ((float)NTOK * (float)DIM));
    out2[1] = perp_acc * (1.0f / (float)QLV);
  }
}

extern "C" void kernel_launch(void* const* d_in, const int* in_sizes, int n_in,
                              void* d_out, int out_size, void* d_ws, size_t ws_size,
                              hipStream_t stream) {
  const float* x = (const float*)d_in[0];
  const float* cb = (const float*)d_in[1];
  float* out = (float*)d_out;
  float* ws = (float*)d_ws;

  float* resid = out;
  float* oidx = out + (size_t)NTOK * DIM;
  float* scal = oidx + (size_t)NTOK * QLV;
  float* counts = ws;
  float* commit = ws + QLV * KCODE;
  int* rcnt = (int*)(ws + QLV * KCODE + QLV);
  float* cnorm = ws + QLV * KCODE + 512;
  int* rlist = (int*)(ws + QLV * KCODE + 512 + QLV * KCODE);
  unsigned short* cbsplit = (unsigned short*)(ws + CBSPLIT_FLOAT_OFF);

  const size_t csplit_floats = (size_t)QLV * NCK * CHUNKB / 4;
  int* cand_cnt = (int*)(ws + CBSPLIT_FLOAT_OFF + csplit_floats);
  int* cand = cand_cnt + NTOK;
  const size_t need_mfma = ((size_t)CBSPLIT_FLOAT_OFF + csplit_floats) * 4;
  const size_t need_cand = need_mfma + (size_t)NTOK * (RCAP + 1) * 4;
  const bool use_mfma = ws_size >= need_mfma;
  const int have_cand = (use_mfma && ws_size >= need_cand) ? 1 : 0;

  hipLaunchKernelGGL(zero_ws, dim3(32), dim3(256), 0, stream, ws);
  hipLaunchKernelGGL(cnorm_np_kernel, dim3((QLV * KCODE) / 256), dim3(256), 0, stream,
                     cb, cnorm);
  if (use_mfma)
    hipLaunchKernelGGL(split_cb_kernel, dim3((QLV * KCODE * DIM / 4) / 256), dim3(256), 0,
                       stream, cb, cbsplit);

  for (int q = 0; q < QLV; ++q) {
    const float* cbq = cb + (size_t)q * KCODE * DIM;
    const float* cnq = cnorm + q * KCODE;
    float* ctq = counts + q * KCODE;
    float* cmq = commit + q;
    int* rcq = rcnt + q;
    const float* rin = (q == 0) ? x : resid;
    if (use_mfma) {
      const unsigned short* csq = cbsplit + (size_t)q * (NCK * CHUNKB / 2);
      if (q == 0)
        hipLaunchKernelGGL((level_mfma<true, false>), dim3(NTOK / BM), dim3(512), 0, stream,
                           x, resid, cbq, csq, cnq, oidx, ctq, cmq, rcq, rlist,
                           cand_cnt, cand, have_cand, q);
      else if (q == QLV - 1)
        hipLaunchKernelGGL((level_mfma<false, true>), dim3(NTOK / BM), dim3(512), 0, stream,
                           x, resid, cbq, csq, cnq, oidx, ctq, cmq, rcq, rlist,
                           cand_cnt, cand, have_cand, q);
      else
        hipLaunchKernelGGL((level_mfma<false, false>), dim3(NTOK / BM), dim3(512), 0, stream,
                           x, resid, cbq, csq, cnq, oidx, ctq, cmq, rcq, rlist,
                           cand_cnt, cand, have_cand, q);
    } else {
      if (q == 0)
        hipLaunchKernelGGL((level_kernel<true, false>), dim3(NTOK / BM), dim3(512), 0, stream,
                           x, resid, cbq, cnq, oidx, ctq, cmq, rcq, rlist, q);
      else if (q == QLV - 1)
        hipLaunchKernelGGL((level_kernel<false, true>), dim3(NTOK / BM), dim3(512), 0, stream,
                           x, resid, cbq, cnq, oidx, ctq, cmq, rcq, rlist, q);
      else
        hipLaunchKernelGGL((level_kernel<false, false>), dim3(NTOK / BM), dim3(512), 0, stream,
                           x, resid, cbq, cnq, oidx, ctq, cmq, rcq, rlist, q);
    }
    if (q == QLV - 1)
      hipLaunchKernelGGL((rescue_np<true>), dim3(256), dim3(256), 0, stream,
                         x, rin, resid, cbq, cnq, oidx, ctq, cmq, rcq, rlist,
                         cand_cnt, cand, have_cand, q);
    else
      hipLaunchKernelGGL((rescue_np<false>), dim3(256), dim3(256), 0, stream,
                         x, rin, resid, cbq, cnq, oidx, ctq, cmq, rcq, rlist,
                         cand_cnt, cand, have_cand, q);
  }
  hipLaunchKernelGGL(finalize_scalars, dim3(1), dim3(256), 0, stream, counts, commit, scal);
}

// Round 4
// 1016.208 us; speedup vs baseline: 2.6314x; 1.0402x over previous
//
#include <hip/hip_runtime.h>
#include <math.h>

#define NTOK 16384
#define DIM 512
#define QLV 8
#define KCODE 1024
#define BM 64
#define DC 8
#define NCH (DIM / DC)  // 64 d-chunks (old path)
#define TAU 1e-3f       // bf16x3 MFMA adds <=2.5e-4 abs error; TAU >= 2*eps

// ---- MFMA path constants ----
#define NCK 16          // 16 chunks of 32 d
#define CHUNKB 131072   // bytes per chunk in split-cb: 2 halves x (hi+lo) x 512 codes x 64 B
#define CBSPLIT_FLOAT_OFF 65536  // float offset of split-cb region inside ws (256 KB in)
#define RCAP 16         // per-token rescue candidate cap

typedef __attribute__((ext_vector_type(4))) float f32x4;
typedef __attribute__((ext_vector_type(8))) short bf16x8;

__global__ __launch_bounds__(256) void zero_ws(float* ws) {
  int i = blockIdx.x * 256 + threadIdx.x;
  for (int k = i; k < QLV * KCODE + 2 * QLV; k += gridDim.x * 256) ws[k] = 0.f;
}

// ---- numpy float32 replication helpers (PROVEN in round 4 — do not touch) --
__device__ __forceinline__ float np_blk128_sq(const float* __restrict__ x) {
#pragma clang fp contract(off)
  float L[16];
#pragma unroll
  for (int j = 0; j < 16; ++j) {
    const float a0 = x[j] * x[j];
    const float a1 = x[16 + j] * x[16 + j];
    const float a2 = x[32 + j] * x[32 + j];
    const float a3 = x[48 + j] * x[48 + j];
    const float a4 = x[64 + j] * x[64 + j];
    const float a5 = x[80 + j] * x[80 + j];
    const float a6 = x[96 + j] * x[96 + j];
    const float a7 = x[112 + j] * x[112 + j];
    L[j] = ((a0 + a1) + (a2 + a3)) + ((a4 + a5) + (a6 + a7));
  }
  float T3[8];
#pragma unroll
  for (int i = 0; i < 8; ++i) T3[i] = L[i] + L[i + 8];
  float T6[4];
#pragma unroll
  for (int j = 0; j < 4; ++j) T6[j] = T3[j] + T3[j + 4];
  return (T6[0] + T6[2]) + (T6[1] + T6[3]);
}

__device__ __forceinline__ float np_sum512_sq(const float* __restrict__ x) {
#pragma clang fp contract(off)
  const float p0 = np_blk128_sq(x);
  const float p1 = np_blk128_sq(x + 128);
  const float p2 = np_blk128_sq(x + 256);
  const float p3 = np_blk128_sq(x + 384);
  const float s01 = p0 + p1;
  const float s23 = p2 + p3;
  return s01 + s23;
}

__device__ __forceinline__ float np_dist(float A, const float* __restrict__ r,
                                         const float* __restrict__ c, float cn) {
#pragma clang fp contract(off)
  float b1 = 0.f;
#pragma unroll 8
  for (int d = 0; d < 384; ++d) b1 = __builtin_fmaf(r[d], c[d], b1);
  float b2 = 0.f;
#pragma unroll 8
  for (int d = 384; d < 512; ++d) b2 = __builtin_fmaf(r[d], c[d], b2);
  const float B = b1 + b2;
  const float t1 = 2.0f * B;
  const float t2 = A - t1;
  return t2 + cn;
}
// ---------------------------------------------------------------------------

__global__ __launch_bounds__(256) void cnorm_np_kernel(const float* __restrict__ cb,
                                                       float* __restrict__ cn) {
  const int row = blockIdx.x * 256 + threadIdx.x;  // [0, Q*K)
  cn[row] = np_sum512_sq(cb + (size_t)row * DIM);
}

// lexicographic (val, idx) less-than
__device__ __forceinline__ bool lt2(float a, int ia, float b, int ib) {
  return a < b || (a == b && ia < ib);
}

// ---- bf16 split helpers (RTNE) ----
__device__ __forceinline__ unsigned short bf16_rtne(float x) {
  unsigned u = __builtin_bit_cast(unsigned, x);
  u += 0x7FFFu + ((u >> 16) & 1u);
  return (unsigned short)(u >> 16);
}
__device__ __forceinline__ float bf16_tof(unsigned short h) {
  unsigned u = (unsigned)h << 16;
  return __builtin_bit_cast(float, u);
}
__device__ __forceinline__ void split2(float x, unsigned short& h, unsigned short& l) {
  h = bf16_rtne(x);
  l = bf16_rtne(x - bf16_tof(h));
}

__device__ __forceinline__ void gload16(const void* g, void* l) {
  __builtin_amdgcn_global_load_lds(
      (const __attribute__((address_space(1))) unsigned int*)g,
      (__attribute__((address_space(3))) unsigned int*)l, 16, 0, 0);
}

// One-time: split fp32 codebooks into pre-swizzled bf16 hi/lo tiles in ws.
// Layout per (q,chunk): [half(2)][hi 32KB | lo 32KB][512 codes][64 B], with
// in-code slot swizzle slot = kb ^ ((cl>>1)&3) so a linear LDS image is
// bank-conflict-free for frag ds_read_b128.
__global__ __launch_bounds__(256) void split_cb_kernel(const float* __restrict__ cb,
                                                       unsigned short* __restrict__ dst) {
  const int f = blockIdx.x * 256 + threadIdx.x;  // float4 index, 2^20 total
  const int d4 = f & 127;
  const int c = (f >> 7) & 1023;
  const int q = f >> 17;
  const float4 v = *(const float4*)(cb + (size_t)f * 4);
  const int d0 = d4 * 4;
  const int dc = d0 >> 5;
  const int e = d0 & 31;
  const int kb = e >> 3;
  const int e7 = e & 7;  // 0 or 4
  const int half = c >> 9, cl = c & 511;
  const int slot = kb ^ ((cl >> 1) & 3);
  const size_t base = (size_t)(q * NCK + dc) * CHUNKB + (size_t)half * 65536;
  const size_t off = base + (size_t)cl * 64 + (size_t)slot * 16 + (size_t)e7 * 2;
  unsigned short h0, l0, h1, l1, h2, l2, h3, l3;
  split2(v.x, h0, l0);
  split2(v.y, h1, l1);
  split2(v.z, h2, l2);
  split2(v.w, h3, l3);
  uint2 hv, lv;
  hv.x = (unsigned)h0 | ((unsigned)h1 << 16);
  hv.y = (unsigned)h2 | ((unsigned)h3 << 16);
  lv.x = (unsigned)l0 | ((unsigned)l1 << 16);
  lv.y = (unsigned)l2 | ((unsigned)l3 << 16);
  char* db = (char*)dst;
  *(uint2*)(db + off) = hv;            // hi plane
  *(uint2*)(db + off + 32768) = lv;    // lo plane
}

// ===================== MFMA level kernel =====================
// Block: 64 tokens x 1024 codes, 512 threads (8 waves).
// Wave w owns code-frags cf = w + 8*j (j=0..7); wave-private LDS ring (8 slots
// x 2KB). Register-double-buffered B: pair j reads pair j+1's frags into the
// spare reg set BEFORE the MFMA cluster, so the ~120cyc ds_read latency hides
// under the 12-MFMA cluster. Counted vmcnt guards the LDS ring (never 0
// mid-loop); one raw s_barrier per 32-d chunk for the shared A tile.
#define VMW(N) asm volatile("s_waitcnt vmcnt(" #N ")" ::: "memory")

template <bool FIRST, bool LAST>
__global__ __launch_bounds__(512, 2) void level_mfma(
    const float* __restrict__ x, float* __restrict__ resid,
    const float* __restrict__ cb, const unsigned short* __restrict__ cbsplit,
    const float* __restrict__ cnorm, float* __restrict__ out_idx,
    float* __restrict__ counts, float* __restrict__ commit, int* __restrict__ rcnt,
    int* __restrict__ rlist, int* __restrict__ cand_cnt, int* __restrict__ cand,
    int have_cand, int qlev) {
  __shared__ __align__(16) unsigned char Bring[8][8][2048];  // [wave][slot][hi1K|lo1K]
  __shared__ __align__(16) unsigned char As[16384];          // [buf][hl][64][64B]
  __shared__ __align__(16) float foldb[64][8][4];
  __shared__ int chosen[64];
  __shared__ float tieV1[64];
  __shared__ int ccnt[64];

  const int tid = threadIdx.x;
  const int lane = tid & 63;
  const int w = tid >> 6;
  const int col = lane & 15;
  const int kb = lane >> 4;
  const int blk = blockIdx.x;
  const float* rin = FIRST ? x : resid;
  const char* csp = (const char*)cbsplit;
  unsigned char* bringw = &Bring[w][0][0];
  const int bcol = col * 64 + ((kb ^ ((col >> 1) & 3)) << 4);
  const int wlo = w * 1024 + lane * 16;  // per-lane B source sub-offset

  // A read offsets (per tf)
  int rdA[4];
#pragma unroll
  for (int tf = 0; tf < 4; ++tf) {
    const int row = tf * 16 + col;
    rdA[tf] = row * 64 + ((kb ^ ((row >> 1) & 3)) << 4);
  }

  // A-staging geometry: thread -> (row, 4 d's)
  const int arow = tid >> 3;
  const int ae0 = (tid & 7) * 4;
  const int akb = ae0 >> 3;
  const int aslot = akb ^ ((arow >> 1) & 3);
  const size_t abyte = (size_t)arow * 64 + (size_t)aslot * 16 + (size_t)(ae0 & 7) * 2;
  const float* aglob = rin + (size_t)(blk * BM + arow) * DIM + ae0;

  f32x4 acc[8][4];
#pragma unroll
  for (int j = 0; j < 8; ++j)
#pragma unroll
    for (int tf = 0; tf < 4; ++tf) acc[j][tf] = (f32x4){0.f, 0.f, 0.f, 0.f};

  bf16x8 bhA, blA, bhB, blB;  // B-fragment register double-buffer

#define LM_ISSUE(PDC, JP)                                                       \
  {                                                                             \
    const char* s_ = csp + (size_t)(PDC)*CHUNKB +                               \
                     (((JP) >> 2) * 65536 + ((JP)&3) * 8192) + wlo;             \
    unsigned char* d_ = bringw + (JP)*2048;                                     \
    gload16(s_, d_);                                                            \
    gload16(s_ + 32768, d_ + 1024);                                             \
  }

#define LM_RD(SLOT, NH, NL)                                   \
  {                                                           \
    const unsigned char* sb_ = bringw + (SLOT)*2048 + bcol;   \
    NH = *(const bf16x8*)sb_;                                 \
    NL = *(const bf16x8*)(sb_ + 1024);                        \
  }

// pass-major MFMA cluster: per-accumulator op sequence identical to the
// original (hi*bh, lo*bh, hi*bl) — bit-identical numerics, but dependent
// ops are 4 apart for latency.
#define LM_MFMA(JJ, CH, CL)                                                              \
  __builtin_amdgcn_sched_barrier(0);                                                     \
  __builtin_amdgcn_s_setprio(1);                                                         \
  acc[JJ][0] = __builtin_amdgcn_mfma_f32_16x16x32_bf16(ah[0], CH, acc[JJ][0], 0, 0, 0);  \
  acc[JJ][1] = __builtin_amdgcn_mfma_f32_16x16x32_bf16(ah[1], CH, acc[JJ][1], 0, 0, 0);  \
  acc[JJ][2] = __builtin_amdgcn_mfma_f32_16x16x32_bf16(ah[2], CH, acc[JJ][2], 0, 0, 0);  \
  acc[JJ][3] = __builtin_amdgcn_mfma_f32_16x16x32_bf16(ah[3], CH, acc[JJ][3], 0, 0, 0);  \
  acc[JJ][0] = __builtin_amdgcn_mfma_f32_16x16x32_bf16(al[0], CH, acc[JJ][0], 0, 0, 0);  \
  acc[JJ][1] = __builtin_amdgcn_mfma_f32_16x16x32_bf16(al[1], CH, acc[JJ][1], 0, 0, 0);  \
  acc[JJ][2] = __builtin_amdgcn_mfma_f32_16x16x32_bf16(al[2], CH, acc[JJ][2], 0, 0, 0);  \
  acc[JJ][3] = __builtin_amdgcn_mfma_f32_16x16x32_bf16(al[3], CH, acc[JJ][3], 0, 0, 0);  \
  acc[JJ][0] = __builtin_amdgcn_mfma_f32_16x16x32_bf16(ah[0], CL, acc[JJ][0], 0, 0, 0);  \
  acc[JJ][1] = __builtin_amdgcn_mfma_f32_16x16x32_bf16(ah[1], CL, acc[JJ][1], 0, 0, 0);  \
  acc[JJ][2] = __builtin_amdgcn_mfma_f32_16x16x32_bf16(ah[2], CL, acc[JJ][2], 0, 0, 0);  \
  acc[JJ][3] = __builtin_amdgcn_mfma_f32_16x16x32_bf16(ah[3], CL, acc[JJ][3], 0, 0, 0);  \
  __builtin_amdgcn_s_setprio(0);

#define LM_ASPLIT(BUF, PSRC)                                       \
  {                                                                \
    unsigned short h0, l0, h1, l1, h2, l2, h3, l3;                 \
    split2((PSRC).x, h0, l0);                                      \
    split2((PSRC).y, h1, l1);                                      \
    split2((PSRC).z, h2, l2);                                      \
    split2((PSRC).w, h3, l3);                                      \
    uint2 hv, lv;                                                  \
    hv.x = (unsigned)h0 | ((unsigned)h1 << 16);                    \
    hv.y = (unsigned)h2 | ((unsigned)h3 << 16);                    \
    lv.x = (unsigned)l0 | ((unsigned)l1 << 16);                    \
    lv.y = (unsigned)l2 | ((unsigned)l3 << 16);                    \
    const size_t ab0_ = (size_t)(BUF)*8192 + abyte;                \
    *(uint2*)&As[ab0_] = hv;                                       \
    *(uint2*)&As[4096 + ab0_] = lv;                                \
  }

  // ---- prologue: A(0)->buf0; issue slots 0..5; preload pair-0 B frags ----
  {
    const float4 pA = *(const float4*)aglob;
    LM_ISSUE(0, 0); LM_ISSUE(0, 1); LM_ISSUE(0, 2);
    LM_ISSUE(0, 3); LM_ISSUE(0, 4); LM_ISSUE(0, 5);
    LM_ASPLIT(0, pA);
  }
  asm volatile("s_waitcnt lgkmcnt(0)" ::: "memory");
  __builtin_amdgcn_s_barrier();
  asm volatile("" ::: "memory");
  VMW(10);             // slot 0 landed (slots 1..5 = 10 ops may remain)
  LM_RD(0, bhA, blA);  // pair 0 current set

  // ---- chunks 0..14 (A prefetch for dc+1) ----
  for (int dc = 0; dc < NCK - 1; ++dc) {
    const int abuf = dc & 1;
    bf16x8 ah[4], al[4];
#pragma unroll
    for (int tf = 0; tf < 4; ++tf) {
      const size_t ab = (size_t)abuf * 8192 + (size_t)rdA[tf];
      ah[tf] = *(const bf16x8*)&As[ab];
      al[tf] = *(const bf16x8*)&As[ab + 4096];
    }
    float4 pAn;
    VMW(8); LM_RD(1, bhB, blB);
    pAn = *(const float4*)(aglob + (dc + 1) * 32);
    LM_ISSUE(dc, 6);
    LM_MFMA(0, bhA, blA);
    VMW(8); LM_RD(2, bhA, blA); LM_ISSUE(dc, 7);     LM_MFMA(1, bhB, blB);
    VMW(8); LM_RD(3, bhB, blB); LM_ISSUE(dc + 1, 0); LM_MFMA(2, bhA, blA);
    VMW(8); LM_RD(4, bhA, blA); LM_ISSUE(dc + 1, 1); LM_MFMA(3, bhB, blB);
    VMW(8); LM_RD(5, bhB, blB); LM_ISSUE(dc + 1, 2); LM_MFMA(4, bhA, blA);
    VMW(8); LM_RD(6, bhA, blA); LM_ISSUE(dc + 1, 3); LM_ASPLIT(abuf ^ 1, pAn); LM_MFMA(5, bhB, blB);
    VMW(8); LM_RD(7, bhB, blB); LM_ISSUE(dc + 1, 4); LM_MFMA(6, bhA, blA);
    VMW(8); LM_RD(0, bhA, blA); LM_ISSUE(dc + 1, 5); LM_MFMA(7, bhB, blB);
    asm volatile("s_waitcnt lgkmcnt(0)" ::: "memory");
    __builtin_amdgcn_s_barrier();
    asm volatile("" ::: "memory");
  }

  // ---- final chunk 15 (tail vmcnt countdown, no A prefetch) ----
  {
    bf16x8 ah[4], al[4];
#pragma unroll
    for (int tf = 0; tf < 4; ++tf) {
      const size_t ab = (size_t)8192 + (size_t)rdA[tf];  // buf 1 (15&1)
      ah[tf] = *(const bf16x8*)&As[ab];
      al[tf] = *(const bf16x8*)&As[ab + 4096];
    }
    VMW(8); LM_RD(1, bhB, blB); LM_ISSUE(15, 6); LM_MFMA(0, bhA, blA);
    VMW(8); LM_RD(2, bhA, blA); LM_ISSUE(15, 7); LM_MFMA(1, bhB, blB);
    VMW(8); LM_RD(3, bhB, blB); LM_MFMA(2, bhA, blA);
    VMW(6); LM_RD(4, bhA, blA); LM_MFMA(3, bhB, blB);
    VMW(4); LM_RD(5, bhB, blB); LM_MFMA(4, bhA, blA);
    VMW(2); LM_RD(6, bhA, blA); LM_MFMA(5, bhB, blB);
    VMW(0); LM_RD(7, bhB, blB); LM_MFMA(6, bhA, blA);
    LM_MFMA(7, bhB, blB);
  }
  __syncthreads();

  // ---- epilogue: fold top-2 per token over this wave's 128 codes ----
  float cnv[8];
#pragma unroll
  for (int j = 0; j < 8; ++j) cnv[j] = cnorm[(w + 8 * j) * 16 + col];

#pragma unroll
  for (int tf = 0; tf < 4; ++tf) {
#pragma unroll
    for (int r = 0; r < 4; ++r) {
      float b1 = 3.4e38f, b2 = 3.4e38f;
      int x1 = KCODE, x2 = KCODE;
#pragma unroll
      for (int j = 0; j < 8; ++j) {
        const int c = (w + 8 * j) * 16 + col;
        const float dist = fmaf(-2.f, acc[j][tf][r], cnv[j]);
        if (lt2(dist, c, b1, x1)) {
          b2 = b1; x2 = x1; b1 = dist; x1 = c;
        } else if (lt2(dist, c, b2, x2)) {
          b2 = dist; x2 = c;
        }
      }
      // butterfly across the 16 lanes of this col-group
#pragma unroll
      for (int off = 1; off < 16; off <<= 1) {
        const float w1 = __shfl_xor(b1, off);
        const int j1 = __shfl_xor(x1, off);
        const float w2 = __shfl_xor(b2, off);
        const int j2 = __shfl_xor(x2, off);
        if (lt2(w1, j1, b1, x1)) {
          if (lt2(b1, x1, w2, j2)) { b2 = b1; x2 = x1; }
          else { b2 = w2; x2 = j2; }
          b1 = w1; x1 = j1;
        } else if (lt2(w1, j1, b2, x2)) {
          b2 = w1; x2 = j1;
        }
      }
      if (col == 0) {
        const int t = tf * 16 + (lane >> 4) * 4 + r;
        float4 fv;
        fv.x = b1; fv.y = __int_as_float(x1); fv.z = b2; fv.w = __int_as_float(x2);
        *(float4*)&foldb[t][w][0] = fv;
      }
    }
  }
  __syncthreads();

  // ---- merge 8 wave-results per token; gap test; decide/rescue ----
  if (tid < 64) {
    float V1 = 3.4e38f, V2 = 3.4e38f;
    int I1 = KCODE, I2 = KCODE;
#pragma unroll
    for (int ww = 0; ww < 8; ++ww) {
      const float4 e = *(const float4*)&foldb[tid][ww][0];
      const float a1 = e.x, a2 = e.z;
      const int a1i = __float_as_int(e.y), a2i = __float_as_int(e.w);
      if (lt2(a1, a1i, V1, I1)) {
        if (lt2(V1, I1, a2, a2i)) { V2 = V1; I2 = I1; }
        else { V2 = a2; I2 = a2i; }
        V1 = a1; I1 = a1i;
      } else if (lt2(a1, a1i, V2, I2)) {
        V2 = a1; I2 = a1i;
      }
    }
    ccnt[tid] = 0;
    tieV1[tid] = V1;
    if (V2 - V1 < TAU) {  // near-tie: np-fp32 rescue decides
      const int pos = atomicAdd(rcnt, 1);
      rlist[pos] = blk * BM + tid;
      chosen[tid] = -1;
    } else {
      chosen[tid] = I1;
      out_idx[(size_t)(blk * BM + tid) * QLV + qlev] = (float)I1;
      atomicAdd(&counts[I1], 1.0f);
    }
  }
  __syncthreads();

  // ---- candidate collection for near-tie tokens (guarded by ws capacity) ----
  if (have_cand) {
#pragma unroll
    for (int tf = 0; tf < 4; ++tf)
#pragma unroll
      for (int r = 0; r < 4; ++r) {
        const int t = tf * 16 + (lane >> 4) * 4 + r;
        if (chosen[t] != -1) continue;
        const float thr = tieV1[t] + TAU;
#pragma unroll
        for (int j = 0; j < 8; ++j) {
          const float dist = fmaf(-2.f, acc[j][tf][r], cnv[j]);
          if (dist < thr) {
            const int c = (w + 8 * j) * 16 + col;
            const int pos = atomicAdd(&ccnt[t], 1);
            if (pos < RCAP) cand[(size_t)(blk * BM + t) * RCAP + pos] = c;
          }
        }
      }
    __syncthreads();
    if (tid < 64 && chosen[tid] == -1) cand_cnt[blk * BM + tid] = ccnt[tid];
  }

  {  // residual update (fp32 chain, bit-equal to np's) — fast-path tokens only
    const int tb = tid >> 3, part = tid & 7;  // 8 threads per token
    const size_t tok = (size_t)(blk * BM + tb);
    const int idx = chosen[tb];
    float sq = 0.f;
    if (idx >= 0) {
      const float4* cp = (const float4*)(cb + (size_t)idx * DIM);
      const float4* rp = (const float4*)(rin + tok * DIM);
      const float4* xp = (const float4*)(x + tok * DIM);
      float4* op = (float4*)(resid + tok * DIM);
#pragma unroll 4
      for (int kk = 0; kk < 16; ++kk) {
        const int d4 = part + kk * 8;
        const float4 r = rp[d4], c4 = cp[d4];
        float4 rn;
        rn.x = r.x - c4.x; rn.y = r.y - c4.y; rn.z = r.z - c4.z; rn.w = r.w - c4.w;
        sq += rn.x * rn.x + rn.y * rn.y + rn.z * rn.z + rn.w * rn.w;
        if (LAST) {
          const float4 xv = xp[d4];
          float4 qv;
          qv.x = xv.x - rn.x; qv.y = xv.y - rn.y; qv.z = xv.z - rn.z; qv.w = xv.w - rn.w;
          op[d4] = qv;  // quantized = x - residual_new
        } else {
          op[d4] = rn;
        }
      }
    }
#pragma unroll
    for (int off = 32; off; off >>= 1) sq += __shfl_down(sq, off);
    if (lane == 0) atomicAdd(commit, sq);
  }
}
#undef LM_ISSUE
#undef LM_RD
#undef LM_MFMA
#undef LM_ASPLIT

// ===================== old fp32 path (fallback if ws too small) =============
template <bool FIRST, bool LAST>
__global__ __launch_bounds__(512, 2) void level_kernel(
    const float* __restrict__ x, float* __restrict__ resid,
    const float* __restrict__ cb, const float* __restrict__ cnorm,
    float* __restrict__ out_idx, float* __restrict__ counts,
    float* __restrict__ commit, int* __restrict__ rcnt,
    int* __restrict__ rlist, int qlev) {
  __shared__ float Rs[DC][BM + 4];
  __shared__ float Cs[DC][KCODE + 4];
  __shared__ int chosen[BM];

  const int tid = threadIdx.x;
  const int lane = tid & 63;
  const int ty = tid >> 6;
  const int tx = lane;
  const int blk = blockIdx.x;
  const float* rin = FIRST ? x : resid;

  float acc[8][16];
#pragma unroll
  for (int j = 0; j < 8; ++j)
#pragma unroll
    for (int g = 0; g < 16; ++g) acc[j][g] = 0.f;

  float4 pc[4];
  float4 pr;
  {
#pragma unroll
    for (int u = 0; u < 4; ++u) {
      const int f4 = tid + u * 512;
      const int code = f4 >> 1, d4 = f4 & 1;
      pc[u] = *(const float4*)(cb + (size_t)code * DIM + d4 * 4);
    }
    if (tid < 128) {
      const int tok = tid >> 1, d4 = tid & 1;
      pr = *(const float4*)(rin + (size_t)(blk * BM + tok) * DIM + d4 * 4);
    }
  }

  for (int dc = 0; dc < NCH; ++dc) {
    __syncthreads();
#pragma unroll
    for (int u = 0; u < 4; ++u) {
      const int f4 = tid + u * 512;
      const int code = f4 >> 1, d4 = f4 & 1;
      Cs[d4 * 4 + 0][code] = pc[u].x;
      Cs[d4 * 4 + 1][code] = pc[u].y;
      Cs[d4 * 4 + 2][code] = pc[u].z;
      Cs[d4 * 4 + 3][code] = pc[u].w;
    }
    if (tid < 128) {
      const int tok = tid >> 1, d4 = tid & 1;
      Rs[d4 * 4 + 0][tok] = pr.x;
      Rs[d4 * 4 + 1][tok] = pr.y;
      Rs[d4 * 4 + 2][tok] = pr.z;
      Rs[d4 * 4 + 3][tok] = pr.w;
    }
    if (dc + 1 < NCH) {
      const int doff = (dc + 1) * DC;
#pragma unroll
      for (int u = 0; u < 4; ++u) {
        const int f4 = tid + u * 512;
        const int code = f4 >> 1, d4 = f4 & 1;
        pc[u] = *(const float4*)(cb + (size_t)code * DIM + doff + d4 * 4);
      }
      if (tid < 128) {
        const int tok = tid >> 1, d4 = tid & 1;
        pr = *(const float4*)(rin + (size_t)(blk * BM + tok) * DIM + doff + d4 * 4);
      }
    }
    __syncthreads();
#pragma unroll
    for (int d = 0; d < DC; ++d) {
      const float4 ra = *(const float4*)&Rs[d][ty * 8];
      const float4 rb = *(const float4*)&Rs[d][ty * 8 + 4];
#pragma unroll
      for (int q = 0; q < 4; ++q) {
        const float4 cv = *(const float4*)&Cs[d][q * 256 + tx * 4];
        const float c0 = cv.x, c1 = cv.y, c2 = cv.z, c3 = cv.w;
        acc[0][q * 4 + 0] = fmaf(ra.x, c0, acc[0][q * 4 + 0]);
        acc[0][q * 4 + 1] = fmaf(ra.x, c1, acc[0][q * 4 + 1]);
        acc[0][q * 4 + 2] = fmaf(ra.x, c2, acc[0][q * 4 + 2]);
        acc[0][q * 4 + 3] = fmaf(ra.x, c3, acc[0][q * 4 + 3]);
        acc[1][q * 4 + 0] = fmaf(ra.y, c0, acc[1][q * 4 + 0]);
        acc[1][q * 4 + 1] = fmaf(ra.y, c1, acc[1][q * 4 + 1]);
        acc[1][q * 4 + 2] = fmaf(ra.y, c2, acc[1][q * 4 + 2]);
        acc[1][q * 4 + 3] = fmaf(ra.y, c3, acc[1][q * 4 + 3]);
        acc[2][q * 4 + 0] = fmaf(ra.z, c0, acc[2][q * 4 + 0]);
        acc[2][q * 4 + 1] = fmaf(ra.z, c1, acc[2][q * 4 + 1]);
        acc[2][q * 4 + 2] = fmaf(ra.z, c2, acc[2][q * 4 + 2]);
        acc[2][q * 4 + 3] = fmaf(ra.z, c3, acc[2][q * 4 + 3]);
        acc[3][q * 4 + 0] = fmaf(ra.w, c0, acc[3][q * 4 + 0]);
        acc[3][q * 4 + 1] = fmaf(ra.w, c1, acc[3][q * 4 + 1]);
        acc[3][q * 4 + 2] = fmaf(ra.w, c2, acc[3][q * 4 + 2]);
        acc[3][q * 4 + 3] = fmaf(ra.w, c3, acc[3][q * 4 + 3]);
        acc[4][q * 4 + 0] = fmaf(rb.x, c0, acc[4][q * 4 + 0]);
        acc[4][q * 4 + 1] = fmaf(rb.x, c1, acc[4][q * 4 + 1]);
        acc[4][q * 4 + 2] = fmaf(rb.x, c2, acc[4][q * 4 + 2]);
        acc[4][q * 4 + 3] = fmaf(rb.x, c3, acc[4][q * 4 + 3]);
        acc[5][q * 4 + 0] = fmaf(rb.y, c0, acc[5][q * 4 + 0]);
        acc[5][q * 4 + 1] = fmaf(rb.y, c1, acc[5][q * 4 + 1]);
        acc[5][q * 4 + 2] = fmaf(rb.y, c2, acc[5][q * 4 + 2]);
        acc[5][q * 4 + 3] = fmaf(rb.y, c3, acc[5][q * 4 + 3]);
        acc[6][q * 4 + 0] = fmaf(rb.z, c0, acc[6][q * 4 + 0]);
        acc[6][q * 4 + 1] = fmaf(rb.z, c1, acc[6][q * 4 + 1]);
        acc[6][q * 4 + 2] = fmaf(rb.z, c2, acc[6][q * 4 + 2]);
        acc[6][q * 4 + 3] = fmaf(rb.z, c3, acc[6][q * 4 + 3]);
        acc[7][q * 4 + 0] = fmaf(rb.w, c0, acc[7][q * 4 + 0]);
        acc[7][q * 4 + 1] = fmaf(rb.w, c1, acc[7][q * 4 + 1]);
        acc[7][q * 4 + 2] = fmaf(rb.w, c2, acc[7][q * 4 + 2]);
        acc[7][q * 4 + 3] = fmaf(rb.w, c3, acc[7][q * 4 + 3]);
      }
    }
  }

  float v1[8], v2[8];
  int i1[8], i2[8];
#pragma unroll
  for (int j = 0; j < 8; ++j) { v1[j] = v2[j] = 3.4e38f; i1[j] = i2[j] = KCODE; }
#pragma unroll
  for (int g = 0; g < 16; ++g) {
    const int c = (g >> 2) * 256 + tx * 4 + (g & 3);
    const float cn = cnorm[c];
#pragma unroll
    for (int j = 0; j < 8; ++j) {
      const float dist = fmaf(-2.f, acc[j][g], cn);
      if (lt2(dist, c, v1[j], i1[j])) {
        v2[j] = v1[j]; i2[j] = i1[j]; v1[j] = dist; i1[j] = c;
      } else if (lt2(dist, c, v2[j], i2[j])) {
        v2[j] = dist; i2[j] = c;
      }
    }
  }
#pragma unroll
  for (int off = 1; off < 64; off <<= 1) {
#pragma unroll
    for (int j = 0; j < 8; ++j) {
      const float w1 = __shfl_xor(v1[j], off);
      const int j1 = __shfl_xor(i1[j], off);
      const float w2 = __shfl_xor(v2[j], off);
      const int j2 = __shfl_xor(i2[j], off);
      if (lt2(w1, j1, v1[j], i1[j])) {
        if (lt2(v1[j], i1[j], w2, j2)) { v2[j] = v1[j]; i2[j] = i1[j]; }
        else { v2[j] = w2; i2[j] = j2; }
        v1[j] = w1; i1[j] = j1;
      } else {
        if (lt2(w1, j1, v2[j], i2[j])) { v2[j] = w1; i2[j] = j1; }
      }
    }
  }
  if (lane < 8) {
    const int tb = ty * 8 + lane;
    const float V1 = v1[lane], V2 = v2[lane];
    const int I1 = i1[lane];
    if (V2 - V1 < TAU) {
      const int pos = atomicAdd(rcnt, 1);
      rlist[pos] = blk * BM + tb;
      chosen[tb] = -1;
    } else {
      chosen[tb] = I1;
      out_idx[(size_t)(blk * BM + tb) * QLV + qlev] = (float)I1;
      atomicAdd(&counts[I1], 1.0f);
    }
  }
  __syncthreads();
  {
    const int tb = tid >> 3, part = tid & 7;
    const size_t tok = (size_t)(blk * BM + tb);
    const int idx = chosen[tb];
    float sq = 0.f;
    if (idx >= 0) {
      const float4* cp = (const float4*)(cb + (size_t)idx * DIM);
      const float4* rp = (const float4*)(rin + tok * DIM);
      const float4* xp = (const float4*)(x + tok * DIM);
      float4* op = (float4*)(resid + tok * DIM);
#pragma unroll 4
      for (int kk = 0; kk < 16; ++kk) {
        const int d4 = part + kk * 8;
        const float4 r = rp[d4], c4 = cp[d4];
        float4 rn;
        rn.x = r.x - c4.x; rn.y = r.y - c4.y; rn.z = r.z - c4.z; rn.w = r.w - c4.w;
        sq += rn.x * rn.x + rn.y * rn.y + rn.z * rn.z + rn.w * rn.w;
        if (LAST) {
          const float4 xv = xp[d4];
          float4 qv;
          qv.x = xv.x - rn.x; qv.y = xv.y - rn.y; qv.z = xv.z - rn.z; qv.w = xv.w - rn.w;
          op[d4] = qv;
        } else {
          op[d4] = rn;
        }
      }
    }
#pragma unroll
    for (int off = 32; off; off >>= 1) sq += __shfl_down(sq, off);
    if (lane == 0) atomicAdd(commit, sq);
  }
}

// Near-tie finalization replicating numpy-fp32 semantics exactly (PROVEN r4).
// Candidate fast path: np-evaluate only the provably-sufficient candidate set.
template <bool LAST>
__global__ __launch_bounds__(256) void rescue_np(
    const float* __restrict__ x, const float* __restrict__ rin,
    float* __restrict__ resid, const float* __restrict__ cbq,
    const float* __restrict__ cnq, float* __restrict__ out_idx,
    float* __restrict__ counts, float* __restrict__ commit,
    const int* __restrict__ rcnt, const int* __restrict__ rlist,
    const int* __restrict__ cand_cnt, const int* __restrict__ cand,
    int have_cand, int qlev) {
  __shared__ float rsh[DIM];
  __shared__ __align__(16) float crows[RCAP][DIM];
  __shared__ float sA;
  __shared__ float wv[4];
  __shared__ int wi[4];
  __shared__ int bestk_s;
  const int tid = threadIdx.x;
  const int n = rcnt[0];
  for (int it = blockIdx.x; it < n; it += gridDim.x) {
    const int t = rlist[it];
    rsh[tid] = rin[(size_t)t * DIM + tid];
    rsh[256 + tid] = rin[(size_t)t * DIM + 256 + tid];
    __syncthreads();
    if (tid == 0) sA = np_sum512_sq(rsh);
    __syncthreads();
    const float A = sA;
    float bv = 3.4e38f;
    int bi = KCODE;
    const int m = have_cand ? cand_cnt[t] : (RCAP + 1);
    if (m <= RCAP) {
      // stage candidate rows into LDS (coalesced), then np_dist each
      for (int c = 0; c < m; ++c) {
        const int k = cand[(size_t)t * RCAP + c];
        crows[c][tid] = cbq[(size_t)k * DIM + tid];
        crows[c][256 + tid] = cbq[(size_t)k * DIM + 256 + tid];
      }
      __syncthreads();
      for (int c = tid; c < m; c += 256) {
        const int k = cand[(size_t)t * RCAP + c];
        const float d = np_dist(A, rsh, &crows[c][0], cnq[k]);
        if (d < bv || (d == bv && k < bi)) { bv = d; bi = k; }
      }
    } else {
      for (int kk = 0; kk < 4; ++kk) {
        const int k = tid * 4 + kk;  // ascending per thread -> first-occurrence ties
        const float d = np_dist(A, rsh, cbq + (size_t)k * DIM, cnq[k]);
        if (d < bv) { bv = d; bi = k; }
      }
    }
#pragma unroll
    for (int off = 32; off; off >>= 1) {
      const float ov = __shfl_down(bv, off);
      const int oi = __shfl_down(bi, off);
      if (ov < bv || (ov == bv && oi < bi)) { bv = ov; bi = oi; }
    }
    if ((tid & 63) == 0) { wv[tid >> 6] = bv; wi[tid >> 6] = bi; }
    __syncthreads();
    if (tid == 0) {
      float V = wv[0]; int I = wi[0];
#pragma unroll
      for (int w = 1; w < 4; ++w)
        if (wv[w] < V || (wv[w] == V && wi[w] < I)) { V = wv[w]; I = wi[w]; }
      bestk_s = I;
      out_idx[(size_t)t * QLV + qlev] = (float)I;
      atomicAdd(&counts[I], 1.0f);
    }
    __syncthreads();
    const float* crow = cbq + (size_t)bestk_s * DIM;
    float sq;
    {
      const int d0 = tid, d1 = tid + 256;
      const float rn0 = rsh[d0] - crow[d0];
      const float rn1 = rsh[d1] - crow[d1];
      sq = rn0 * rn0 + rn1 * rn1;
      if (LAST) {
        resid[(size_t)t * DIM + d0] = x[(size_t)t * DIM + d0] - rn0;
        resid[(size_t)t * DIM + d1] = x[(size_t)t * DIM + d1] - rn1;
      } else {
        resid[(size_t)t * DIM + d0] = rn0;
        resid[(size_t)t * DIM + d1] = rn1;
      }
    }
#pragma unroll
    for (int off = 32; off; off >>= 1) sq += __shfl_down(sq, off);
    if ((tid & 63) == 0) wv[tid >> 6] = sq;
    __syncthreads();
    if (tid == 0)
      atomicAdd(commit, wv[0] + wv[1] + wv[2] + wv[3]);
    __syncthreads();  // protect rsh/crows/wv before next list item
  }
}

__global__ __launch_bounds__(256) void finalize_scalars(const float* __restrict__ counts,
                                                        const float* __restrict__ commit,
                                                        float* __restrict__ out2) {
  const int tid = threadIdx.x;
  __shared__ float sh[4];
  __shared__ float perp_acc;
  if (tid == 0) perp_acc = 0.f;
  __syncthreads();
  for (int q = 0; q < QLV; ++q) {
    float h = 0.f;
    for (int k = tid; k < KCODE; k += 256) {
      const float p = counts[q * KCODE + k] * (1.0f / (float)NTOK);
      h += p * logf(p + 1e-10f);
    }
#pragma unroll
    for (int off = 32; off; off >>= 1) h += __shfl_down(h, off);
    if ((tid & 63) == 0) sh[tid >> 6] = h;
    __syncthreads();
    if (tid == 0) {
      const float H = sh[0] + sh[1] + sh[2] + sh[3];
      perp_acc += expf(-H);
    }
    __syncthreads();
  }
  if (tid == 0) {
    float closs = 0.f;
    for (int q = 0; q < QLV; ++q) closs += commit[q];
    out2[0] = closs * (0.25f / ((float)NTOK * (float)DIM));
    out2[1] = perp_acc * (1.0f / (float)QLV);
  }
}

extern "C" void kernel_launch(void* const* d_in, const int* in_sizes, int n_in,
                              void* d_out, int out_size, void* d_ws, size_t ws_size,
                              hipStream_t stream) {
  const float* x = (const float*)d_in[0];
  const float* cb = (const float*)d_in[1];
  float* out = (float*)d_out;
  float* ws = (float*)d_ws;

  float* resid = out;
  float* oidx = out + (size_t)NTOK * DIM;
  float* scal = oidx + (size_t)NTOK * QLV;
  float* counts = ws;
  float* commit = ws + QLV * KCODE;
  int* rcnt = (int*)(ws + QLV * KCODE + QLV);
  float* cnorm = ws + QLV * KCODE + 512;
  int* rlist = (int*)(ws + QLV * KCODE + 512 + QLV * KCODE);
  unsigned short* cbsplit = (unsigned short*)(ws + CBSPLIT_FLOAT_OFF);

  const size_t csplit_floats = (size_t)QLV * NCK * CHUNKB / 4;
  int* cand_cnt = (int*)(ws + CBSPLIT_FLOAT_OFF + csplit_floats);
  int* cand = cand_cnt + NTOK;
  const size_t need_mfma = ((size_t)CBSPLIT_FLOAT_OFF + csplit_floats) * 4;
  const size_t need_cand = need_mfma + (size_t)NTOK * (RCAP + 1) * 4;
  const bool use_mfma = ws_size >= need_mfma;
  const int have_cand = (use_mfma && ws_size >= need_cand) ? 1 : 0;

  hipLaunchKernelGGL(zero_ws, dim3(32), dim3(256), 0, stream, ws);
  hipLaunchKernelGGL(cnorm_np_kernel, dim3((QLV * KCODE) / 256), dim3(256), 0, stream,
                     cb, cnorm);
  if (use_mfma)
    hipLaunchKernelGGL(split_cb_kernel, dim3((QLV * KCODE * DIM / 4) / 256), dim3(256), 0,
                       stream, cb, cbsplit);

  for (int q = 0; q < QLV; ++q) {
    const float* cbq = cb + (size_t)q * KCODE * DIM;
    const float* cnq = cnorm + q * KCODE;
    float* ctq = counts + q * KCODE;
    float* cmq = commit + q;
    int* rcq = rcnt + q;
    const float* rin = (q == 0) ? x : resid;
    if (use_mfma) {
      const unsigned short* csq = cbsplit + (size_t)q * (NCK * CHUNKB / 2);
      if (q == 0)
        hipLaunchKernelGGL((level_mfma<true, false>), dim3(NTOK / BM), dim3(512), 0, stream,
                           x, resid, cbq, csq, cnq, oidx, ctq, cmq, rcq, rlist,
                           cand_cnt, cand, have_cand, q);
      else if (q == QLV - 1)
        hipLaunchKernelGGL((level_mfma<false, true>), dim3(NTOK / BM), dim3(512), 0, stream,
                           x, resid, cbq, csq, cnq, oidx, ctq, cmq, rcq, rlist,
                           cand_cnt, cand, have_cand, q);
      else
        hipLaunchKernelGGL((level_mfma<false, false>), dim3(NTOK / BM), dim3(512), 0, stream,
                           x, resid, cbq, csq, cnq, oidx, ctq, cmq, rcq, rlist,
                           cand_cnt, cand, have_cand, q);
    } else {
      if (q == 0)
        hipLaunchKernelGGL((level_kernel<true, false>), dim3(NTOK / BM), dim3(512), 0, stream,
                           x, resid, cbq, cnq, oidx, ctq, cmq, rcq, rlist, q);
      else if (q == QLV - 1)
        hipLaunchKernelGGL((level_kernel<false, true>), dim3(NTOK / BM), dim3(512), 0, stream,
                           x, resid, cbq, cnq, oidx, ctq, cmq, rcq, rlist, q);
      else
        hipLaunchKernelGGL((level_kernel<false, false>), dim3(NTOK / BM), dim3(512), 0, stream,
                           x, resid, cbq, cnq, oidx, ctq, cmq, rcq, rlist, q);
    }
    if (q == QLV - 1)
      hipLaunchKernelGGL((rescue_np<true>), dim3(256), dim3(256), 0, stream,
                         x, rin, resid, cbq, cnq, oidx, ctq, cmq, rcq, rlist,
                         cand_cnt, cand, have_cand, q);
    else
      hipLaunchKernelGGL((rescue_np<false>), dim3(256), dim3(256), 0, stream,
                         x, rin, resid, cbq, cnq, oidx, ctq, cmq, rcq, rlist,
                         cand_cnt, cand, have_cand, q);
  }
  hipLaunchKernelGGL(finalize_scalars, dim3(1), dim3(256), 0, stream, counts, commit, scal);
}